// Round 1
// baseline (1405.289 us; speedup 1.0000x reference)
//
#include <hip/hip_runtime.h>
#include <cstdint>
#include <cstddef>

#define D 64

// ---------------- degree / CSR build ----------------

__global__ void k_indeg(const int* __restrict__ col, int* __restrict__ indeg, int E) {
    int e = blockIdx.x * 256 + threadIdx.x;
    if (e < E) atomicAdd(&indeg[col[e]], 1);
}

__global__ void k_scan1(const int* __restrict__ indeg, int* __restrict__ bsum, int N) {
    __shared__ int s[256];
    int t = threadIdx.x;
    int base = blockIdx.x * 2048 + t * 8;
    int sum = 0;
#pragma unroll
    for (int j = 0; j < 8; ++j) { int i = base + j; if (i < N) sum += indeg[i]; }
    s[t] = sum; __syncthreads();
    for (int off = 128; off > 0; off >>= 1) {
        if (t < off) s[t] += s[t + off];
        __syncthreads();
    }
    if (t == 0) bsum[blockIdx.x] = s[0];
}

__global__ void k_scan2(int* bsum, int nb, int* offs, int N) {
    if (threadIdx.x == 0 && blockIdx.x == 0) {
        int run = 0;
        for (int i = 0; i < nb; ++i) { int v = bsum[i]; bsum[i] = run; run += v; }
        offs[N] = run;
    }
}

__global__ void k_scan3(const int* __restrict__ indeg, const int* __restrict__ bsum,
                        int* __restrict__ offs, int N) {
    __shared__ int s[256];
    int t = threadIdx.x;
    int base = blockIdx.x * 2048 + t * 8;
    int v[8]; int sum = 0;
#pragma unroll
    for (int j = 0; j < 8; ++j) { int i = base + j; v[j] = (i < N) ? indeg[i] : 0; sum += v[j]; }
    s[t] = sum; __syncthreads();
    for (int off = 1; off < 256; off <<= 1) {
        int x = (t >= off) ? s[t - off] : 0;
        __syncthreads();
        s[t] += x;
        __syncthreads();
    }
    int run = bsum[blockIdx.x] + (s[t] - sum);
#pragma unroll
    for (int j = 0; j < 8; ++j) { int i = base + j; if (i < N) offs[i] = run; run += v[j]; }
}

__global__ void k_dis(const int* __restrict__ indeg, float* __restrict__ dis, int N) {
    int i = blockIdx.x * 256 + threadIdx.x;
    if (i < N) dis[i] = rsqrtf((float)(indeg[i] + 1));
}

__global__ void k_bin(const int* __restrict__ row, const int* __restrict__ col,
                      const int* __restrict__ offs, int* __restrict__ cursor,
                      int* __restrict__ csrc, int E) {
    int e = blockIdx.x * 256 + threadIdx.x;
    if (e < E) {
        int c = col[e];
        int pos = offs[c] + atomicAdd(&cursor[c], 1);
        csrc[pos] = row[e];
    }
}

// fold BN (eval) + conv bias into per-channel scale/shift:
// y = (agg + b - mean) * gamma*rsqrt(var+eps) + beta = agg*sc + sh
__global__ void k_bnprep(const float* __restrict__ cb, const float* __restrict__ g,
                         const float* __restrict__ be, const float* __restrict__ mu,
                         const float* __restrict__ var, float* __restrict__ sc,
                         float* __restrict__ sh, int LD) {
    int i = blockIdx.x * 256 + threadIdx.x;
    if (i < LD) {
        float s = g[i] * rsqrtf(var[i] + 1e-5f);
        sc[i] = s;
        sh[i] = (cb[i] - mu[i]) * s + be[i];
    }
}

// ---------------- conv GEMM: xw' = (A @ W) * dis[row],  K=D=64 ----------------

__global__ __launch_bounds__(256) void k_conv(const float* __restrict__ A, int lda,
                                              const float* __restrict__ W,
                                              const float* __restrict__ dis,
                                              float* __restrict__ out, int N) {
    __shared__ float At[64][68];   // transposed [k][m], 16B-aligned rows
    __shared__ float Wl[64][64];   // [k][n]
    int t = threadIdx.x;
    int bm = blockIdx.x * 64;
    {
        int row = t >> 2, kc = (t & 3) * 16;
        int r = bm + row;
        float v[16];
        if (r < N) {
            const float* p = A + (size_t)r * lda + kc;
#pragma unroll
            for (int j = 0; j < 16; j += 4) {
                float4 x = *(const float4*)(p + j);
                v[j] = x.x; v[j + 1] = x.y; v[j + 2] = x.z; v[j + 3] = x.w;
            }
        } else {
#pragma unroll
            for (int j = 0; j < 16; ++j) v[j] = 0.f;
        }
#pragma unroll
        for (int j = 0; j < 16; ++j) At[kc + j][row] = v[j];
        const float* wp = W + row * 64 + kc;
#pragma unroll
        for (int j = 0; j < 16; j += 4)
            *(float4*)&Wl[row][kc + j] = *(const float4*)(wp + j);
    }
    __syncthreads();
    int m0 = (t & 15) * 4, n0 = (t >> 4) * 4;
    float acc[4][4];
#pragma unroll
    for (int i = 0; i < 4; ++i)
#pragma unroll
        for (int j = 0; j < 4; ++j) acc[i][j] = 0.f;
#pragma unroll 8
    for (int kk = 0; kk < 64; ++kk) {
        float4 a = *(const float4*)&At[kk][m0];
        float4 b = *(const float4*)&Wl[kk][n0];
        float av[4] = {a.x, a.y, a.z, a.w};
        float bv[4] = {b.x, b.y, b.z, b.w};
#pragma unroll
        for (int i = 0; i < 4; ++i)
#pragma unroll
            for (int j = 0; j < 4; ++j) acc[i][j] = fmaf(av[i], bv[j], acc[i][j]);
    }
#pragma unroll
    for (int i = 0; i < 4; ++i) {
        int r = bm + m0 + i;
        if (r < N) {
            float dv = dis[r];
            float4 o;
            o.x = acc[i][0] * dv; o.y = acc[i][1] * dv;
            o.z = acc[i][2] * dv; o.w = acc[i][3] * dv;
            *(float4*)&out[(size_t)r * 64 + n0] = o;
        }
    }
}

// ---------------- aggregation: CSR gather + self loop + BN + relu + skip ----------------

__global__ void k_agg(const float* __restrict__ xw, const int* __restrict__ offs,
                      const int* __restrict__ src, const float* __restrict__ dis,
                      const float* __restrict__ sc, const float* __restrict__ sh,
                      const float* __restrict__ skip, float* __restrict__ out,
                      int ld, int N) {
    int t = threadIdx.x;
    int v = blockIdx.x * 16 + (t >> 4);
    if (v >= N) return;
    int c0 = (t & 15) * 4;
    const float* xp = xw + c0;
    float4 a = *(const float4*)(xp + (size_t)v * 64);   // self loop (xw' pre-scaled by dis)
    float ax = a.x, ay = a.y, az = a.z, aw = a.w;
    int e0 = offs[v], e1 = offs[v + 1];
    int e = e0;
    for (; e + 1 < e1; e += 2) {
        int s0 = src[e], s1 = src[e + 1];
        float4 m0 = *(const float4*)(xp + (size_t)s0 * 64);
        float4 m1 = *(const float4*)(xp + (size_t)s1 * 64);
        ax += m0.x + m1.x; ay += m0.y + m1.y;
        az += m0.z + m1.z; aw += m0.w + m1.w;
    }
    if (e < e1) {
        int s0 = src[e];
        float4 m0 = *(const float4*)(xp + (size_t)s0 * 64);
        ax += m0.x; ay += m0.y; az += m0.z; aw += m0.w;
    }
    float dv = dis[v];
    float4 S = *(const float4*)&sc[c0];
    float4 H = *(const float4*)&sh[c0];
    float y0 = fmaxf(fmaf(ax * dv, S.x, H.x), 0.f);
    float y1 = fmaxf(fmaf(ay * dv, S.y, H.y), 0.f);
    float y2 = fmaxf(fmaf(az * dv, S.z, H.z), 0.f);
    float y3 = fmaxf(fmaf(aw * dv, S.w, H.w), 0.f);
    size_t ob = (size_t)v * ld + c0;
    if (skip) {
        const float4 s4 = *(const float4*)(skip + ob);
        y0 += s4.x; y1 += s4.y; y2 += s4.z; y3 += s4.w;
    }
    float4 o; o.x = y0; o.y = y1; o.z = y2; o.w = y3;
    *(float4*)(out + ob) = o;
}

// ---------------- encoder GEMM: C = relu(A @ B + bias), BM=BN=64, BK=32 ----------------

__global__ __launch_bounds__(256) void k_enc(const float* __restrict__ A, int lda,
                                             const float* __restrict__ B, int ldb,
                                             const float* __restrict__ bias,
                                             float* __restrict__ C, int ldc,
                                             int M, int K) {
    __shared__ float At[32][68];
    __shared__ float Bl[32][64];
    int t = threadIdx.x;
    int bm = blockIdx.x * 64;
    int bn = blockIdx.y * 64;
    int m0 = (t & 15) * 4, n0 = (t >> 4) * 4;
    float acc[4][4];
#pragma unroll
    for (int i = 0; i < 4; ++i)
#pragma unroll
        for (int j = 0; j < 4; ++j) acc[i][j] = 0.f;
    int arow = t >> 2, akc = (t & 3) * 8;
    int brow = t >> 3, bcc = (t & 7) * 8;
    int r = bm + arow;
    const float* ap = A + (size_t)r * lda + akc;
    const float* bp = B + (size_t)brow * ldb + bn + bcc;
    for (int k0 = 0; k0 < K; k0 += 32) {
        float av[8];
        if (r < M) {
            float4 x0 = *(const float4*)(ap + k0);
            float4 x1 = *(const float4*)(ap + k0 + 4);
            av[0] = x0.x; av[1] = x0.y; av[2] = x0.z; av[3] = x0.w;
            av[4] = x1.x; av[5] = x1.y; av[6] = x1.z; av[7] = x1.w;
        } else {
#pragma unroll
            for (int j = 0; j < 8; ++j) av[j] = 0.f;
        }
        float4 b0 = *(const float4*)(bp + (size_t)k0 * ldb);
        float4 b1 = *(const float4*)(bp + (size_t)k0 * ldb + 4);
        __syncthreads();
#pragma unroll
        for (int j = 0; j < 8; ++j) At[akc + j][arow] = av[j];
        *(float4*)&Bl[brow][bcc] = b0;
        *(float4*)&Bl[brow][bcc + 4] = b1;
        __syncthreads();
#pragma unroll
        for (int kk = 0; kk < 32; ++kk) {
            float4 a = *(const float4*)&At[kk][m0];
            float4 b = *(const float4*)&Bl[kk][n0];
            float avv[4] = {a.x, a.y, a.z, a.w};
            float bvv[4] = {b.x, b.y, b.z, b.w};
#pragma unroll
            for (int i = 0; i < 4; ++i)
#pragma unroll
                for (int j = 0; j < 4; ++j) acc[i][j] = fmaf(avv[i], bvv[j], acc[i][j]);
        }
    }
#pragma unroll
    for (int i = 0; i < 4; ++i) {
        int rr = bm + m0 + i;
        if (rr < M) {
            float4 o;
            o.x = fmaxf(acc[i][0] + bias[bn + n0 + 0], 0.f);
            o.y = fmaxf(acc[i][1] + bias[bn + n0 + 1], 0.f);
            o.z = fmaxf(acc[i][2] + bias[bn + n0 + 2], 0.f);
            o.w = fmaxf(acc[i][3] + bias[bn + n0 + 3], 0.f);
            *(float4*)&C[(size_t)rr * ldc + bn + n0] = o;
        }
    }
}

// ---------------- graph mean-pool (batch sorted -> segment accumulate) ----------------

__global__ void k_pool(const float* __restrict__ h2, const int* __restrict__ batch,
                       float* __restrict__ gsum, int* __restrict__ gcnt, int H, int N) {
    int c = threadIdx.x;  // 0..H-1
    int n0 = blockIdx.x * 512;
    if (n0 >= N) return;
    int n1 = n0 + 512; if (n1 > N) n1 = N;
    float acc = 0.f;
    int cur = batch[n0];
    int cnt = 0;
    for (int n = n0; n < n1; ++n) {
        int g = batch[n];
        if (g != cur) {
            atomicAdd(&gsum[(size_t)cur * H + c], acc);
            if (c == 0) atomicAdd(&gcnt[cur], cnt);
            acc = 0.f; cnt = 0; cur = g;
        }
        acc += h2[(size_t)n * H + c];
        ++cnt;
    }
    atomicAdd(&gsum[(size_t)cur * H + c], acc);
    if (c == 0) atomicAdd(&gcnt[cur], cnt);
}

// ---------------- decoder: out = relu(gfeat @ W1 + b1) @ W2 + b2 ----------------

__global__ void k_dec(const float* __restrict__ gsum, const int* __restrict__ gcnt,
                      const float* __restrict__ W1, const float* __restrict__ b1,
                      const float* __restrict__ W2, const float* __restrict__ b2,
                      float* __restrict__ out, int H, int HD) {
    int g = blockIdx.x;
    int t = threadIdx.x;  // 0..HD-1 (64)
    float cnt = (float)gcnt[g];
    float inv = 1.0f / fmaxf(cnt, 1.0f);
    float hid = b1[t];
    for (int k = 0; k < H; ++k) {
        float gf = gsum[(size_t)g * H + k] * inv;
        hid = fmaf(gf, W1[k * HD + t], hid);
    }
    hid = fmaxf(hid, 0.f);
    float p = hid * W2[t];
    for (int off = 32; off > 0; off >>= 1) p += __shfl_down(p, off);
    if (t == 0) out[g] = p + b2[0];
}

// ---------------- host ----------------

extern "C" void kernel_launch(void* const* d_in, const int* in_sizes, int n_in,
                              void* d_out, int out_size, void* d_ws, size_t ws_size,
                              hipStream_t stream) {
    const float* x     = (const float*)d_in[0];
    const int*   ei    = (const int*)d_in[1];
    const int*   batch = (const int*)d_in[2];
    const float* convW = (const float*)d_in[3];
    const float* convb = (const float*)d_in[4];
    const float* gamma = (const float*)d_in[5];
    const float* beta  = (const float*)d_in[6];
    const float* mean  = (const float*)d_in[7];
    const float* var   = (const float*)d_in[8];
    const float* eW1   = (const float*)d_in[9];
    const float* eb1   = (const float*)d_in[10];
    const float* eW2   = (const float*)d_in[11];
    const float* eb2   = (const float*)d_in[12];
    const float* dW1   = (const float*)d_in[13];
    const float* db1   = (const float*)d_in[14];
    const float* dW2   = (const float*)d_in[15];
    const float* db2   = (const float*)d_in[16];

    int N  = in_sizes[0] / D;
    int E  = in_sizes[1] / 2;
    int L  = in_sizes[3] / (D * D);
    int G  = out_size;
    int LD = L * D;                 // 256
    int H1 = in_sizes[10];          // 256
    int H2 = in_sizes[12];          // 128
    int HD = in_sizes[14];          // 64 (decoder hidden)

    char* ws = (char*)d_ws;
    size_t off = 0;
    auto alloc = [&](size_t b) -> void* {
        void* p = ws + off;
        off += (b + 255) & ~(size_t)255;
        return p;
    };
    float* local  = (float*)alloc((size_t)N * LD * 4);   // layer outputs concat; later reused as h2
    float* bufB   = (float*)alloc((size_t)N * LD * 4);   // xw (N*64) then h1 (N*256)
    int*   csrc   = (int*)alloc((size_t)E * 4);
    float* dis    = (float*)alloc((size_t)N * 4);
    int*   indeg  = (int*)alloc((size_t)N * 4);
    int*   offs   = (int*)alloc((size_t)(N + 1) * 4);
    int*   cursor = (int*)alloc((size_t)N * 4);
    int nb = (N + 2047) / 2048;
    int*   bsum   = (int*)alloc((size_t)nb * 4);
    float* sc     = (float*)alloc((size_t)LD * 4);
    float* sh     = (float*)alloc((size_t)LD * 4);
    float* gsum   = (float*)alloc((size_t)G * H2 * 4);
    int*   gcnt   = (int*)alloc((size_t)G * 4);
    float* xw = bufB;
    float* h1 = bufB;
    float* h2 = local;   // safe: `local` dead after enc1 reads it

    // zero accumulators (ws is poisoned before every call)
    hipMemsetAsync(indeg, 0, (size_t)N * 4, stream);
    hipMemsetAsync(cursor, 0, (size_t)N * 4, stream);
    hipMemsetAsync(gsum, 0, (size_t)G * H2 * 4, stream);
    hipMemsetAsync(gcnt, 0, (size_t)G * 4, stream);

    int tE = (E + 255) / 256;
    k_indeg<<<tE, 256, 0, stream>>>(ei + E, indeg, E);
    k_scan1<<<nb, 256, 0, stream>>>(indeg, bsum, N);
    k_scan2<<<1, 64, 0, stream>>>(bsum, nb, offs, N);
    k_scan3<<<nb, 256, 0, stream>>>(indeg, bsum, offs, N);
    k_dis<<<(N + 255) / 256, 256, 0, stream>>>(indeg, dis, N);
    k_bin<<<tE, 256, 0, stream>>>(ei, ei + E, offs, cursor, csrc, E);
    k_bnprep<<<(LD + 255) / 256, 256, 0, stream>>>(convb, gamma, beta, mean, var, sc, sh, LD);

    for (int l = 0; l < L; ++l) {
        const float* Ain = (l == 0) ? x : (local + (size_t)(l - 1) * D);
        int lda = (l == 0) ? D : LD;
        k_conv<<<(N + 63) / 64, 256, 0, stream>>>(Ain, lda, convW + (size_t)l * D * D, dis, xw, N);
        const float* skip = (l % 2 == 0 && l != 0 && l != L - 1) ? (local + (size_t)(l - 2) * D) : nullptr;
        k_agg<<<(N + 15) / 16, 256, 0, stream>>>(xw, offs, csrc, dis, sc + (size_t)l * D,
                                                 sh + (size_t)l * D, skip,
                                                 local + (size_t)l * D, LD, N);
    }

    dim3 ge1((N + 63) / 64, H1 / 64);
    k_enc<<<ge1, 256, 0, stream>>>(local, LD, eW1, H1, eb1, h1, H1, N, LD);
    dim3 ge2((N + 63) / 64, H2 / 64);
    k_enc<<<ge2, 256, 0, stream>>>(h1, H1, eW2, H2, eb2, h2, H2, N, H1);

    k_pool<<<(N + 511) / 512, H2, 0, stream>>>(h2, batch, gsum, gcnt, H2, N);
    k_dec<<<G, HD, 0, stream>>>(gsum, gcnt, dW1, db1, dW2, db2, (float*)d_out, H2, HD);
}

// Round 2
// 1385.181 us; speedup vs baseline: 1.0145x; 1.0145x over previous
//
#include <hip/hip_runtime.h>
#include <cstdint>
#include <cstddef>

#define D 64

typedef __attribute__((ext_vector_type(8))) short short8;
typedef __attribute__((ext_vector_type(4))) float floatx4;

// ---------------- degree / CSR build ----------------

__global__ void k_indeg(const int* __restrict__ col, int* __restrict__ indeg, int E) {
    int e = blockIdx.x * 256 + threadIdx.x;
    if (e < E) atomicAdd(&indeg[col[e]], 1);
}

__global__ void k_scan1(const int* __restrict__ indeg, int* __restrict__ bsum, int N) {
    __shared__ int s[256];
    int t = threadIdx.x;
    int base = blockIdx.x * 2048 + t * 8;
    int sum = 0;
#pragma unroll
    for (int j = 0; j < 8; ++j) { int i = base + j; if (i < N) sum += indeg[i]; }
    s[t] = sum; __syncthreads();
    for (int off = 128; off > 0; off >>= 1) {
        if (t < off) s[t] += s[t + off];
        __syncthreads();
    }
    if (t == 0) bsum[blockIdx.x] = s[0];
}

__global__ void k_scan2(int* bsum, int nb, int* offs, int N) {
    if (threadIdx.x == 0 && blockIdx.x == 0) {
        int run = 0;
        for (int i = 0; i < nb; ++i) { int v = bsum[i]; bsum[i] = run; run += v; }
        offs[N] = run;
    }
}

__global__ void k_scan3(const int* __restrict__ indeg, const int* __restrict__ bsum,
                        int* __restrict__ offs, int N) {
    __shared__ int s[256];
    int t = threadIdx.x;
    int base = blockIdx.x * 2048 + t * 8;
    int v[8]; int sum = 0;
#pragma unroll
    for (int j = 0; j < 8; ++j) { int i = base + j; v[j] = (i < N) ? indeg[i] : 0; sum += v[j]; }
    s[t] = sum; __syncthreads();
    for (int off = 1; off < 256; off <<= 1) {
        int x = (t >= off) ? s[t - off] : 0;
        __syncthreads();
        s[t] += x;
        __syncthreads();
    }
    int run = bsum[blockIdx.x] + (s[t] - sum);
#pragma unroll
    for (int j = 0; j < 8; ++j) { int i = base + j; if (i < N) offs[i] = run; run += v[j]; }
}

__global__ void k_dis(const int* __restrict__ indeg, float* __restrict__ dis, int N) {
    int i = blockIdx.x * 256 + threadIdx.x;
    if (i < N) dis[i] = rsqrtf((float)(indeg[i] + 1));
}

__global__ void k_bin(const int* __restrict__ row, const int* __restrict__ col,
                      const int* __restrict__ offs, int* __restrict__ cursor,
                      int* __restrict__ csrc, int E) {
    int e = blockIdx.x * 256 + threadIdx.x;
    if (e < E) {
        int c = col[e];
        int pos = offs[c] + atomicAdd(&cursor[c], 1);
        csrc[pos] = row[e];
    }
}

// fold BN (eval) + conv bias into per-channel scale/shift
__global__ void k_bnprep(const float* __restrict__ cb, const float* __restrict__ g,
                         const float* __restrict__ be, const float* __restrict__ mu,
                         const float* __restrict__ var, float* __restrict__ sc,
                         float* __restrict__ sh, int LD) {
    int i = blockIdx.x * 256 + threadIdx.x;
    if (i < LD) {
        float s = g[i] * rsqrtf(var[i] + 1e-5f);
        sc[i] = s;
        sh[i] = (cb[i] - mu[i]) * s + be[i];
    }
}

// split fp32 weights into bf16 hi/lo, stored TRANSPOSED [n][k] for direct b128 frag loads
__global__ void k_wsplit(const float* __restrict__ B, unsigned short* __restrict__ hiT,
                         unsigned short* __restrict__ loT, int K, int Nc, int nshift) {
    int idx = blockIdx.x * 256 + threadIdx.x;
    if (idx >= K * Nc) return;
    int k = idx >> nshift;
    int n = idx & (Nc - 1);
    float a = B[idx];
    unsigned b = __float_as_uint(a);
    unsigned hb = b & 0xFFFF0000u;
    float ah = __uint_as_float(hb);
    float al = a - ah;
    hiT[(size_t)n * K + k] = (unsigned short)(hb >> 16);
    loT[(size_t)n * K + k] = (unsigned short)(__float_as_uint(al) >> 16);
}

// ---------------- conv GEMM: xw' = (A @ W) * dis[row],  K=D=64 ----------------

__global__ __launch_bounds__(256) void k_conv(const float* __restrict__ A, int lda,
                                              const float* __restrict__ W,
                                              const float* __restrict__ dis,
                                              float* __restrict__ out, int N) {
    __shared__ float At[64][68];
    __shared__ float Wl[64][64];
    int t = threadIdx.x;
    int bm = blockIdx.x * 64;
    {
        int row = t >> 2, kc = (t & 3) * 16;
        int r = bm + row;
        float v[16];
        if (r < N) {
            const float* p = A + (size_t)r * lda + kc;
#pragma unroll
            for (int j = 0; j < 16; j += 4) {
                float4 x = *(const float4*)(p + j);
                v[j] = x.x; v[j + 1] = x.y; v[j + 2] = x.z; v[j + 3] = x.w;
            }
        } else {
#pragma unroll
            for (int j = 0; j < 16; ++j) v[j] = 0.f;
        }
#pragma unroll
        for (int j = 0; j < 16; ++j) At[kc + j][row] = v[j];
        const float* wp = W + row * 64 + kc;
#pragma unroll
        for (int j = 0; j < 16; j += 4)
            *(float4*)&Wl[row][kc + j] = *(const float4*)(wp + j);
    }
    __syncthreads();
    int m0 = (t & 15) * 4, n0 = (t >> 4) * 4;
    float acc[4][4];
#pragma unroll
    for (int i = 0; i < 4; ++i)
#pragma unroll
        for (int j = 0; j < 4; ++j) acc[i][j] = 0.f;
#pragma unroll 8
    for (int kk = 0; kk < 64; ++kk) {
        float4 a = *(const float4*)&At[kk][m0];
        float4 b = *(const float4*)&Wl[kk][n0];
        float av[4] = {a.x, a.y, a.z, a.w};
        float bv[4] = {b.x, b.y, b.z, b.w};
#pragma unroll
        for (int i = 0; i < 4; ++i)
#pragma unroll
            for (int j = 0; j < 4; ++j) acc[i][j] = fmaf(av[i], bv[j], acc[i][j]);
    }
#pragma unroll
    for (int i = 0; i < 4; ++i) {
        int r = bm + m0 + i;
        if (r < N) {
            float dv = dis[r];
            float4 o;
            o.x = acc[i][0] * dv; o.y = acc[i][1] * dv;
            o.z = acc[i][2] * dv; o.w = acc[i][3] * dv;
            *(float4*)&out[(size_t)r * 64 + n0] = o;
        }
    }
}

// ---------------- aggregation: CSR gather + self loop + BN + relu + skip ----------------

__global__ void k_agg(const float* __restrict__ xw, const int* __restrict__ offs,
                      const int* __restrict__ src, const float* __restrict__ dis,
                      const float* __restrict__ sc, const float* __restrict__ sh,
                      const float* __restrict__ skip, float* __restrict__ out,
                      int ld, int N) {
    int t = threadIdx.x;
    int v = blockIdx.x * 16 + (t >> 4);
    if (v >= N) return;
    int c0 = (t & 15) * 4;
    const float* xp = xw + c0;
    float4 a = *(const float4*)(xp + (size_t)v * 64);   // self loop
    float ax = a.x, ay = a.y, az = a.z, aw = a.w;
    int e0 = offs[v], e1 = offs[v + 1];
    int e = e0;
    // deep unroll: 8 outstanding gathers to hide L2/L3 latency
    for (; e + 8 <= e1; e += 8) {
        int s0 = src[e],     s1 = src[e + 1], s2 = src[e + 2], s3 = src[e + 3];
        int s4 = src[e + 4], s5 = src[e + 5], s6 = src[e + 6], s7 = src[e + 7];
        float4 m0 = *(const float4*)(xp + (size_t)s0 * 64);
        float4 m1 = *(const float4*)(xp + (size_t)s1 * 64);
        float4 m2 = *(const float4*)(xp + (size_t)s2 * 64);
        float4 m3 = *(const float4*)(xp + (size_t)s3 * 64);
        float4 m4 = *(const float4*)(xp + (size_t)s4 * 64);
        float4 m5 = *(const float4*)(xp + (size_t)s5 * 64);
        float4 m6 = *(const float4*)(xp + (size_t)s6 * 64);
        float4 m7 = *(const float4*)(xp + (size_t)s7 * 64);
        ax += ((m0.x + m1.x) + (m2.x + m3.x)) + ((m4.x + m5.x) + (m6.x + m7.x));
        ay += ((m0.y + m1.y) + (m2.y + m3.y)) + ((m4.y + m5.y) + (m6.y + m7.y));
        az += ((m0.z + m1.z) + (m2.z + m3.z)) + ((m4.z + m5.z) + (m6.z + m7.z));
        aw += ((m0.w + m1.w) + (m2.w + m3.w)) + ((m4.w + m5.w) + (m6.w + m7.w));
    }
    for (; e < e1; ++e) {
        int s0 = src[e];
        float4 m0 = *(const float4*)(xp + (size_t)s0 * 64);
        ax += m0.x; ay += m0.y; az += m0.z; aw += m0.w;
    }
    float dv = dis[v];
    float4 S = *(const float4*)&sc[c0];
    float4 H = *(const float4*)&sh[c0];
    float y0 = fmaxf(fmaf(ax * dv, S.x, H.x), 0.f);
    float y1 = fmaxf(fmaf(ay * dv, S.y, H.y), 0.f);
    float y2 = fmaxf(fmaf(az * dv, S.z, H.z), 0.f);
    float y3 = fmaxf(fmaf(aw * dv, S.w, H.w), 0.f);
    size_t ob = (size_t)v * ld + c0;
    if (skip) {
        const float4 s4 = *(const float4*)(skip + ob);
        y0 += s4.x; y1 += s4.y; y2 += s4.z; y3 += s4.w;
    }
    float4 o; o.x = y0; o.y = y1; o.z = y2; o.w = y3;
    *(float4*)(out + ob) = o;
}

// ---------------- encoder GEMM via bf16x3-split MFMA ----------------
// C = relu(A @ B + bias); A fp32 [M,K] split on the fly; B pre-split bf16 hi/lo,
// transposed [n][k]. Block: 256 thr = 4 waves; BM=128 (32 rows/wave), BN=64.
// Per wave: acc 2x4 frags of 16x16; 3 MFMAs per frag per 32-K chunk (hi*hi+hi*lo+lo*hi).

__device__ inline void split8(const float* __restrict__ p, bool valid,
                              short8& hi, short8& lo) {
    float v[8];
    if (valid) {
        float4 x0 = *(const float4*)p;
        float4 x1 = *(const float4*)(p + 4);
        v[0] = x0.x; v[1] = x0.y; v[2] = x0.z; v[3] = x0.w;
        v[4] = x1.x; v[5] = x1.y; v[6] = x1.z; v[7] = x1.w;
    } else {
#pragma unroll
        for (int j = 0; j < 8; ++j) v[j] = 0.f;
    }
#pragma unroll
    for (int j = 0; j < 8; ++j) {
        unsigned b = __float_as_uint(v[j]);
        unsigned hb = b & 0xFFFF0000u;
        hi[j] = (short)(hb >> 16);
        float al = v[j] - __uint_as_float(hb);
        lo[j] = (short)(__float_as_uint(al) >> 16);
    }
}

__global__ __launch_bounds__(256) void k_encm(const float* __restrict__ A, int lda,
                                              int M, int K,
                                              const unsigned short* __restrict__ BhiT,
                                              const unsigned short* __restrict__ BloT,
                                              const float* __restrict__ bias,
                                              float* __restrict__ C, int ldc) {
    int t = threadIdx.x;
    int lane = t & 63;
    int w = t >> 6;
    int bm = blockIdx.x * 128 + w * 32;
    int bn = blockIdx.y * 64;
    int l16 = lane & 15;
    int quad = lane >> 4;

    floatx4 acc[2][4];
#pragma unroll
    for (int i = 0; i < 2; ++i)
#pragma unroll
        for (int j = 0; j < 4; ++j) acc[i][j] = (floatx4)0.f;

    int m0 = bm + l16;
    int m1 = bm + 16 + l16;
    bool v0 = m0 < M, v1 = m1 < M;
    const float* a0p = A + (size_t)(v0 ? m0 : 0) * lda + quad * 8;
    const float* a1p = A + (size_t)(v1 ? m1 : 0) * lda + quad * 8;
    const unsigned short* bp[4];
#pragma unroll
    for (int j = 0; j < 4; ++j)
        bp[j] = BhiT + (size_t)(bn + j * 16 + l16) * K + quad * 8;
    size_t loOff = (size_t)(BloT - BhiT);

#pragma unroll 2
    for (int k0 = 0; k0 < K; k0 += 32) {
        short8 ah0, al0, ah1, al1;
        split8(a0p + k0, v0, ah0, al0);
        split8(a1p + k0, v1, ah1, al1);
        short8 bh[4], bl[4];
#pragma unroll
        for (int j = 0; j < 4; ++j) {
            bh[j] = *(const short8*)(bp[j] + k0);
            bl[j] = *(const short8*)(bp[j] + loOff + k0);
        }
#pragma unroll
        for (int j = 0; j < 4; ++j) {
            acc[0][j] = __builtin_amdgcn_mfma_f32_16x16x32_bf16(al0, bh[j], acc[0][j], 0, 0, 0);
            acc[0][j] = __builtin_amdgcn_mfma_f32_16x16x32_bf16(ah0, bl[j], acc[0][j], 0, 0, 0);
            acc[0][j] = __builtin_amdgcn_mfma_f32_16x16x32_bf16(ah0, bh[j], acc[0][j], 0, 0, 0);
            acc[1][j] = __builtin_amdgcn_mfma_f32_16x16x32_bf16(al1, bh[j], acc[1][j], 0, 0, 0);
            acc[1][j] = __builtin_amdgcn_mfma_f32_16x16x32_bf16(ah1, bl[j], acc[1][j], 0, 0, 0);
            acc[1][j] = __builtin_amdgcn_mfma_f32_16x16x32_bf16(ah1, bh[j], acc[1][j], 0, 0, 0);
        }
    }

#pragma unroll
    for (int i = 0; i < 2; ++i) {
#pragma unroll
        for (int r = 0; r < 4; ++r) {
            int m = bm + i * 16 + quad * 4 + r;
            if (m < M) {
                float* cp = C + (size_t)m * ldc + bn + l16;
#pragma unroll
                for (int j = 0; j < 4; ++j)
                    cp[j * 16] = fmaxf(acc[i][j][r] + bias[bn + j * 16 + l16], 0.f);
            }
        }
    }
}

// ---------------- graph mean-pool (batch sorted -> segment accumulate) ----------------

__global__ void k_pool(const float* __restrict__ h2, const int* __restrict__ batch,
                       float* __restrict__ gsum, int* __restrict__ gcnt, int H, int N) {
    int c = threadIdx.x;
    int n0 = blockIdx.x * 512;
    if (n0 >= N) return;
    int n1 = n0 + 512; if (n1 > N) n1 = N;
    float acc = 0.f;
    int cur = batch[n0];
    int cnt = 0;
    for (int n = n0; n < n1; ++n) {
        int g = batch[n];
        if (g != cur) {
            atomicAdd(&gsum[(size_t)cur * H + c], acc);
            if (c == 0) atomicAdd(&gcnt[cur], cnt);
            acc = 0.f; cnt = 0; cur = g;
        }
        acc += h2[(size_t)n * H + c];
        ++cnt;
    }
    atomicAdd(&gsum[(size_t)cur * H + c], acc);
    if (c == 0) atomicAdd(&gcnt[cur], cnt);
}

// ---------------- decoder ----------------

__global__ void k_dec(const float* __restrict__ gsum, const int* __restrict__ gcnt,
                      const float* __restrict__ W1, const float* __restrict__ b1,
                      const float* __restrict__ W2, const float* __restrict__ b2,
                      float* __restrict__ out, int H, int HD) {
    int g = blockIdx.x;
    int t = threadIdx.x;
    float cnt = (float)gcnt[g];
    float inv = 1.0f / fmaxf(cnt, 1.0f);
    float hid = b1[t];
    for (int k = 0; k < H; ++k) {
        float gf = gsum[(size_t)g * H + k] * inv;
        hid = fmaf(gf, W1[k * HD + t], hid);
    }
    hid = fmaxf(hid, 0.f);
    float p = hid * W2[t];
    for (int off = 32; off > 0; off >>= 1) p += __shfl_down(p, off);
    if (t == 0) out[g] = p + b2[0];
}

// ---------------- host ----------------

extern "C" void kernel_launch(void* const* d_in, const int* in_sizes, int n_in,
                              void* d_out, int out_size, void* d_ws, size_t ws_size,
                              hipStream_t stream) {
    const float* x     = (const float*)d_in[0];
    const int*   ei    = (const int*)d_in[1];
    const int*   batch = (const int*)d_in[2];
    const float* convW = (const float*)d_in[3];
    const float* convb = (const float*)d_in[4];
    const float* gamma = (const float*)d_in[5];
    const float* beta  = (const float*)d_in[6];
    const float* mean  = (const float*)d_in[7];
    const float* var   = (const float*)d_in[8];
    const float* eW1   = (const float*)d_in[9];
    const float* eb1   = (const float*)d_in[10];
    const float* eW2   = (const float*)d_in[11];
    const float* eb2   = (const float*)d_in[12];
    const float* dW1   = (const float*)d_in[13];
    const float* db1   = (const float*)d_in[14];
    const float* dW2   = (const float*)d_in[15];
    const float* db2   = (const float*)d_in[16];

    int N  = in_sizes[0] / D;
    int E  = in_sizes[1] / 2;
    int L  = in_sizes[3] / (D * D);
    int G  = out_size;
    int LD = L * D;                 // 256
    int H1 = in_sizes[10];          // 256
    int H2 = in_sizes[12];          // 128
    int HD = in_sizes[14];          // 64

    char* ws = (char*)d_ws;
    size_t off = 0;
    auto alloc = [&](size_t b) -> void* {
        void* p = ws + off;
        off += (b + 255) & ~(size_t)255;
        return p;
    };
    float* local  = (float*)alloc((size_t)N * LD * 4);   // layer outputs; later reused as h2
    float* bufB   = (float*)alloc((size_t)N * LD * 4);   // xw then h1
    int*   csrc   = (int*)alloc((size_t)E * 4);
    float* dis    = (float*)alloc((size_t)N * 4);
    int*   indeg  = (int*)alloc((size_t)N * 4);
    int*   offs   = (int*)alloc((size_t)(N + 1) * 4);
    int*   cursor = (int*)alloc((size_t)N * 4);
    int nb = (N + 2047) / 2048;
    int*   bsum   = (int*)alloc((size_t)nb * 4);
    float* sc     = (float*)alloc((size_t)LD * 4);
    float* sh     = (float*)alloc((size_t)LD * 4);
    float* gsum   = (float*)alloc((size_t)G * H2 * 4);
    int*   gcnt   = (int*)alloc((size_t)G * 4);
    unsigned short* w1hi = (unsigned short*)alloc((size_t)LD * H1 * 2);
    unsigned short* w1lo = (unsigned short*)alloc((size_t)LD * H1 * 2);
    unsigned short* w2hi = (unsigned short*)alloc((size_t)H1 * H2 * 2);
    unsigned short* w2lo = (unsigned short*)alloc((size_t)H1 * H2 * 2);
    float* xw = bufB;
    float* h1 = bufB;
    float* h2 = local;

    hipMemsetAsync(indeg, 0, (size_t)N * 4, stream);
    hipMemsetAsync(cursor, 0, (size_t)N * 4, stream);
    hipMemsetAsync(gsum, 0, (size_t)G * H2 * 4, stream);
    hipMemsetAsync(gcnt, 0, (size_t)G * 4, stream);

    int tE = (E + 255) / 256;
    k_indeg<<<tE, 256, 0, stream>>>(ei + E, indeg, E);
    k_scan1<<<nb, 256, 0, stream>>>(indeg, bsum, N);
    k_scan2<<<1, 64, 0, stream>>>(bsum, nb, offs, N);
    k_scan3<<<nb, 256, 0, stream>>>(indeg, bsum, offs, N);
    k_dis<<<(N + 255) / 256, 256, 0, stream>>>(indeg, dis, N);
    k_bin<<<tE, 256, 0, stream>>>(ei, ei + E, offs, cursor, csrc, E);
    k_bnprep<<<(LD + 255) / 256, 256, 0, stream>>>(convb, gamma, beta, mean, var, sc, sh, LD);
    k_wsplit<<<(LD * H1 + 255) / 256, 256, 0, stream>>>(eW1, w1hi, w1lo, LD, H1, 8);
    k_wsplit<<<(H1 * H2 + 255) / 256, 256, 0, stream>>>(eW2, w2hi, w2lo, H1, H2, 7);

    for (int l = 0; l < L; ++l) {
        const float* Ain = (l == 0) ? x : (local + (size_t)(l - 1) * D);
        int lda = (l == 0) ? D : LD;
        k_conv<<<(N + 63) / 64, 256, 0, stream>>>(Ain, lda, convW + (size_t)l * D * D, dis, xw, N);
        const float* skip = (l % 2 == 0 && l != 0 && l != L - 1) ? (local + (size_t)(l - 2) * D) : nullptr;
        k_agg<<<(N + 15) / 16, 256, 0, stream>>>(xw, offs, csrc, dis, sc + (size_t)l * D,
                                                 sh + (size_t)l * D, skip,
                                                 local + (size_t)l * D, LD, N);
    }

    dim3 ge1((N + 127) / 128, H1 / 64);
    k_encm<<<ge1, 256, 0, stream>>>(local, LD, N, LD, w1hi, w1lo, eb1, h1, H1);
    dim3 ge2((N + 127) / 128, H2 / 64);
    k_encm<<<ge2, 256, 0, stream>>>(h1, H1, N, H1, w2hi, w2lo, eb2, h2, H2);

    k_pool<<<(N + 511) / 512, H2, 0, stream>>>(h2, batch, gsum, gcnt, H2, N);
    k_dec<<<G, HD, 0, stream>>>(gsum, gcnt, dW1, db1, dW2, db2, (float*)d_out, H2, HD);
}

// Round 3
// 1314.004 us; speedup vs baseline: 1.0695x; 1.0542x over previous
//
#include <hip/hip_runtime.h>
#include <cstdint>
#include <cstddef>

#define D 64

typedef __attribute__((ext_vector_type(8))) short short8;
typedef __attribute__((ext_vector_type(4))) float floatx4;

// ---------------- degree / CSR build ----------------

__global__ void k_indeg(const int* __restrict__ col, int* __restrict__ indeg, int E) {
    int e = blockIdx.x * 256 + threadIdx.x;
    if (e < E) atomicAdd(&indeg[col[e]], 1);
}

__global__ void k_scan1(const int* __restrict__ indeg, int* __restrict__ bsum, int N) {
    __shared__ int s[256];
    int t = threadIdx.x;
    int base = blockIdx.x * 2048 + t * 8;
    int sum = 0;
#pragma unroll
    for (int j = 0; j < 8; ++j) { int i = base + j; if (i < N) sum += indeg[i]; }
    s[t] = sum; __syncthreads();
    for (int off = 128; off > 0; off >>= 1) {
        if (t < off) s[t] += s[t + off];
        __syncthreads();
    }
    if (t == 0) bsum[blockIdx.x] = s[0];
}

__global__ void k_scan2(int* bsum, int nb, int* offs, int N) {
    if (threadIdx.x == 0 && blockIdx.x == 0) {
        int run = 0;
        for (int i = 0; i < nb; ++i) { int v = bsum[i]; bsum[i] = run; run += v; }
        offs[N] = run;
    }
}

__global__ void k_scan3(const int* __restrict__ indeg, const int* __restrict__ bsum,
                        int* __restrict__ offs, int N) {
    __shared__ int s[256];
    int t = threadIdx.x;
    int base = blockIdx.x * 2048 + t * 8;
    int v[8]; int sum = 0;
#pragma unroll
    for (int j = 0; j < 8; ++j) { int i = base + j; v[j] = (i < N) ? indeg[i] : 0; sum += v[j]; }
    s[t] = sum; __syncthreads();
    for (int off = 1; off < 256; off <<= 1) {
        int x = (t >= off) ? s[t - off] : 0;
        __syncthreads();
        s[t] += x;
        __syncthreads();
    }
    int run = bsum[blockIdx.x] + (s[t] - sum);
#pragma unroll
    for (int j = 0; j < 8; ++j) { int i = base + j; if (i < N) offs[i] = run; run += v[j]; }
}

__global__ void k_dis(const int* __restrict__ indeg, float* __restrict__ dis, int N) {
    int i = blockIdx.x * 256 + threadIdx.x;
    if (i < N) dis[i] = rsqrtf((float)(indeg[i] + 1));
}

__global__ void k_bin(const int* __restrict__ row, const int* __restrict__ col,
                      const int* __restrict__ offs, int* __restrict__ cursor,
                      int* __restrict__ csrc, int E) {
    int e = blockIdx.x * 256 + threadIdx.x;
    if (e < E) {
        int c = col[e];
        int pos = offs[c] + atomicAdd(&cursor[c], 1);
        csrc[pos] = row[e];
    }
}

// fold BN (eval) + conv bias into per-channel scale/shift
__global__ void k_bnprep(const float* __restrict__ cb, const float* __restrict__ g,
                         const float* __restrict__ be, const float* __restrict__ mu,
                         const float* __restrict__ var, float* __restrict__ sc,
                         float* __restrict__ sh, int LD) {
    int i = blockIdx.x * 256 + threadIdx.x;
    if (i < LD) {
        float s = g[i] * rsqrtf(var[i] + 1e-5f);
        sc[i] = s;
        sh[i] = (cb[i] - mu[i]) * s + be[i];
    }
}

// split fp32 weights into bf16 hi/lo, stored TRANSPOSED [n][k] for direct b128 frag loads
__global__ void k_wsplit(const float* __restrict__ B, unsigned short* __restrict__ hiT,
                         unsigned short* __restrict__ loT, int K, int Nc, int nshift) {
    int idx = blockIdx.x * 256 + threadIdx.x;
    if (idx >= K * Nc) return;
    int k = idx >> nshift;
    int n = idx & (Nc - 1);
    float a = B[idx];
    unsigned b = __float_as_uint(a);
    unsigned hb = b & 0xFFFF0000u;
    float ah = __uint_as_float(hb);
    float al = a - ah;
    hiT[(size_t)n * K + k] = (unsigned short)(hb >> 16);
    loT[(size_t)n * K + k] = (unsigned short)(__float_as_uint(al) >> 16);
}

// ---------------- conv GEMM: xw' = (A @ W) * dis[row],  K=D=64 ----------------

__global__ __launch_bounds__(256) void k_conv(const float* __restrict__ A, int lda,
                                              const float* __restrict__ W,
                                              const float* __restrict__ dis,
                                              float* __restrict__ out, int N) {
    __shared__ float At[64][68];
    __shared__ float Wl[64][64];
    int t = threadIdx.x;
    int bm = blockIdx.x * 64;
    {
        int row = t >> 2, kc = (t & 3) * 16;
        int r = bm + row;
        float v[16];
        if (r < N) {
            const float* p = A + (size_t)r * lda + kc;
#pragma unroll
            for (int j = 0; j < 16; j += 4) {
                float4 x = *(const float4*)(p + j);
                v[j] = x.x; v[j + 1] = x.y; v[j + 2] = x.z; v[j + 3] = x.w;
            }
        } else {
#pragma unroll
            for (int j = 0; j < 16; ++j) v[j] = 0.f;
        }
#pragma unroll
        for (int j = 0; j < 16; ++j) At[kc + j][row] = v[j];
        const float* wp = W + row * 64 + kc;
#pragma unroll
        for (int j = 0; j < 16; j += 4)
            *(float4*)&Wl[row][kc + j] = *(const float4*)(wp + j);
    }
    __syncthreads();
    int m0 = (t & 15) * 4, n0 = (t >> 4) * 4;
    float acc[4][4];
#pragma unroll
    for (int i = 0; i < 4; ++i)
#pragma unroll
        for (int j = 0; j < 4; ++j) acc[i][j] = 0.f;
#pragma unroll 8
    for (int kk = 0; kk < 64; ++kk) {
        float4 a = *(const float4*)&At[kk][m0];
        float4 b = *(const float4*)&Wl[kk][n0];
        float av[4] = {a.x, a.y, a.z, a.w};
        float bv[4] = {b.x, b.y, b.z, b.w};
#pragma unroll
        for (int i = 0; i < 4; ++i)
#pragma unroll
            for (int j = 0; j < 4; ++j) acc[i][j] = fmaf(av[i], bv[j], acc[i][j]);
    }
#pragma unroll
    for (int i = 0; i < 4; ++i) {
        int r = bm + m0 + i;
        if (r < N) {
            float dv = dis[r];
            float4 o;
            o.x = acc[i][0] * dv; o.y = acc[i][1] * dv;
            o.z = acc[i][2] * dv; o.w = acc[i][3] * dv;
            *(float4*)&out[(size_t)r * 64 + n0] = o;
        }
    }
}

// ---------------- aggregation: CSR gather + self loop + BN + relu + skip ----------------

__global__ void k_agg(const float* __restrict__ xw, const int* __restrict__ offs,
                      const int* __restrict__ src, const float* __restrict__ dis,
                      const float* __restrict__ sc, const float* __restrict__ sh,
                      const float* __restrict__ skip, float* __restrict__ out,
                      int ld, int N) {
    int t = threadIdx.x;
    int v = blockIdx.x * 16 + (t >> 4);
    if (v >= N) return;
    int c0 = (t & 15) * 4;
    const float* xp = xw + c0;
    float4 a = *(const float4*)(xp + (size_t)v * 64);   // self loop
    float ax = a.x, ay = a.y, az = a.z, aw = a.w;
    int e0 = offs[v], e1 = offs[v + 1];
    int e = e0;
    // deep unroll: 8 outstanding gathers to hide L2/L3 latency
    for (; e + 8 <= e1; e += 8) {
        int s0 = src[e],     s1 = src[e + 1], s2 = src[e + 2], s3 = src[e + 3];
        int s4 = src[e + 4], s5 = src[e + 5], s6 = src[e + 6], s7 = src[e + 7];
        float4 m0 = *(const float4*)(xp + (size_t)s0 * 64);
        float4 m1 = *(const float4*)(xp + (size_t)s1 * 64);
        float4 m2 = *(const float4*)(xp + (size_t)s2 * 64);
        float4 m3 = *(const float4*)(xp + (size_t)s3 * 64);
        float4 m4 = *(const float4*)(xp + (size_t)s4 * 64);
        float4 m5 = *(const float4*)(xp + (size_t)s5 * 64);
        float4 m6 = *(const float4*)(xp + (size_t)s6 * 64);
        float4 m7 = *(const float4*)(xp + (size_t)s7 * 64);
        ax += ((m0.x + m1.x) + (m2.x + m3.x)) + ((m4.x + m5.x) + (m6.x + m7.x));
        ay += ((m0.y + m1.y) + (m2.y + m3.y)) + ((m4.y + m5.y) + (m6.y + m7.y));
        az += ((m0.z + m1.z) + (m2.z + m3.z)) + ((m4.z + m5.z) + (m6.z + m7.z));
        aw += ((m0.w + m1.w) + (m2.w + m3.w)) + ((m4.w + m5.w) + (m6.w + m7.w));
    }
    for (; e < e1; ++e) {
        int s0 = src[e];
        float4 m0 = *(const float4*)(xp + (size_t)s0 * 64);
        ax += m0.x; ay += m0.y; az += m0.z; aw += m0.w;
    }
    float dv = dis[v];
    float4 S = *(const float4*)&sc[c0];
    float4 H = *(const float4*)&sh[c0];
    float y0 = fmaxf(fmaf(ax * dv, S.x, H.x), 0.f);
    float y1 = fmaxf(fmaf(ay * dv, S.y, H.y), 0.f);
    float y2 = fmaxf(fmaf(az * dv, S.z, H.z), 0.f);
    float y3 = fmaxf(fmaf(aw * dv, S.w, H.w), 0.f);
    size_t ob = (size_t)v * ld + c0;
    if (skip) {
        const float4 s4 = *(const float4*)(skip + ob);
        y0 += s4.x; y1 += s4.y; y2 += s4.z; y3 += s4.w;
    }
    float4 o; o.x = y0; o.y = y1; o.z = y2; o.w = y3;
    *(float4*)(out + ob) = o;
}

// ---------------- encoder GEMM via bf16x3-split MFMA, LDS-staged A ----------------
// One block covers the FULL N width: A row-panel fetched+split ONCE into LDS,
// shared by 4 waves. NWN = waves across n (4 -> BM=32, 2 -> BM=64 with 2 m-groups).
// LDS layout (16B short8 units): u = kc*PS + row*5 + quad, PS = BM*5+1
// (row stride 5 units -> lane rows spread across all banks; +1 plane pad).

__global__ __launch_bounds__(256) void k_encm(const float* __restrict__ A, int lda,
                                              int M, int K,
                                              const unsigned short* __restrict__ BhiT,
                                              const unsigned short* __restrict__ BloT,
                                              const float* __restrict__ bias,
                                              float* __restrict__ C, int ldc, int NWN) {
    extern __shared__ char smem[];
    const int BM = 128 / NWN;          // 32 or 64
    const int PS = BM * 5 + 1;
    short8* Ah = (short8*)smem;
    short8* Al = Ah + 4 * PS;

    int t = threadIdx.x;
    int lane = t & 63;
    int l16 = lane & 15;
    int quad = lane >> 4;
    int w = t >> 6;
    int nw = w % NWN;
    int mw = (w / NWN) * 32;           // wave's m-group base within panel
    int bm = blockIdx.x * BM;
    int n0 = nw * 64;

    floatx4 acc[2][4];
#pragma unroll
    for (int i = 0; i < 2; ++i)
#pragma unroll
        for (int j = 0; j < 4; ++j) acc[i][j] = (floatx4)0.f;

    const unsigned short* bp[4];
#pragma unroll
    for (int j = 0; j < 4; ++j)
        bp[j] = BhiT + (size_t)(n0 + j * 16 + l16) * K + quad * 8;
    size_t loOff = (size_t)(BloT - BhiT);

    const int ngroups = BM / 32;       // staging groups per thread
    int grow = t >> 3;                 // row within 32-row group (8 thr/row)
    int c0 = (t & 7) * 16;             // 16-float column chunk

    for (int k0 = 0; k0 < K; k0 += 128) {
        if (k0) __syncthreads();
        // ---- stage & split A panel [BM x 128] ----
        for (int g = 0; g < ngroups; ++g) {
            int row = g * 32 + grow;
            int r = bm + row;
            float v[16];
            if (r < M) {
                const float* p = A + (size_t)r * lda + k0 + c0;
#pragma unroll
                for (int j = 0; j < 16; j += 4) {
                    float4 x = *(const float4*)(p + j);
                    v[j] = x.x; v[j + 1] = x.y; v[j + 2] = x.z; v[j + 3] = x.w;
                }
            } else {
#pragma unroll
                for (int j = 0; j < 16; ++j) v[j] = 0.f;
            }
#pragma unroll
            for (int q = 0; q < 2; ++q) {
                short8 hi, lo;
#pragma unroll
                for (int jj = 0; jj < 8; ++jj) {
                    float a = v[q * 8 + jj];
                    unsigned b = __float_as_uint(a);
                    unsigned hb = b & 0xFFFF0000u;
                    hi[jj] = (short)(hb >> 16);
                    float al = a - __uint_as_float(hb);
                    lo[jj] = (short)(__float_as_uint(al) >> 16);
                }
                int cc = c0 + q * 8;
                int u = (cc >> 5) * PS + row * 5 + ((cc & 31) >> 3);
                Ah[u] = hi;
                Al[u] = lo;
            }
        }
        __syncthreads();
        // ---- compute on the staged tile ----
#pragma unroll
        for (int kc = 0; kc < 4; ++kc) {
            int ub0 = kc * PS + (mw + l16) * 5 + quad;
            int ub1 = kc * PS + (mw + 16 + l16) * 5 + quad;
            short8 ah0 = Ah[ub0];
            short8 ah1 = Ah[ub1];
            short8 al0 = Al[ub0];
            short8 al1 = Al[ub1];
            int koff = k0 + kc * 32;
            short8 bh[4], bl[4];
#pragma unroll
            for (int j = 0; j < 4; ++j) {
                bh[j] = *(const short8*)(bp[j] + koff);
                bl[j] = *(const short8*)(bp[j] + loOff + koff);
            }
#pragma unroll
            for (int j = 0; j < 4; ++j) {
                acc[0][j] = __builtin_amdgcn_mfma_f32_16x16x32_bf16(al0, bh[j], acc[0][j], 0, 0, 0);
                acc[0][j] = __builtin_amdgcn_mfma_f32_16x16x32_bf16(ah0, bl[j], acc[0][j], 0, 0, 0);
                acc[0][j] = __builtin_amdgcn_mfma_f32_16x16x32_bf16(ah0, bh[j], acc[0][j], 0, 0, 0);
                acc[1][j] = __builtin_amdgcn_mfma_f32_16x16x32_bf16(al1, bh[j], acc[1][j], 0, 0, 0);
                acc[1][j] = __builtin_amdgcn_mfma_f32_16x16x32_bf16(ah1, bl[j], acc[1][j], 0, 0, 0);
                acc[1][j] = __builtin_amdgcn_mfma_f32_16x16x32_bf16(ah1, bh[j], acc[1][j], 0, 0, 0);
            }
        }
    }

#pragma unroll
    for (int i = 0; i < 2; ++i) {
#pragma unroll
        for (int r = 0; r < 4; ++r) {
            int m = bm + mw + i * 16 + quad * 4 + r;
            if (m < M) {
                float* cp = C + (size_t)m * ldc + n0 + l16;
#pragma unroll
                for (int j = 0; j < 4; ++j)
                    cp[j * 16] = fmaxf(acc[i][j][r] + bias[n0 + j * 16 + l16], 0.f);
            }
        }
    }
}

// ---------------- graph mean-pool (batch sorted -> segment accumulate) ----------------

__global__ void k_pool(const float* __restrict__ h2, const int* __restrict__ batch,
                       float* __restrict__ gsum, int* __restrict__ gcnt, int H, int N) {
    int c = threadIdx.x;
    int n0 = blockIdx.x * 512;
    if (n0 >= N) return;
    int n1 = n0 + 512; if (n1 > N) n1 = N;
    float acc = 0.f;
    int cur = batch[n0];
    int cnt = 0;
    for (int n = n0; n < n1; ++n) {
        int g = batch[n];
        if (g != cur) {
            atomicAdd(&gsum[(size_t)cur * H + c], acc);
            if (c == 0) atomicAdd(&gcnt[cur], cnt);
            acc = 0.f; cnt = 0; cur = g;
        }
        acc += h2[(size_t)n * H + c];
        ++cnt;
    }
    atomicAdd(&gsum[(size_t)cur * H + c], acc);
    if (c == 0) atomicAdd(&gcnt[cur], cnt);
}

// ---------------- decoder ----------------

__global__ void k_dec(const float* __restrict__ gsum, const int* __restrict__ gcnt,
                      const float* __restrict__ W1, const float* __restrict__ b1,
                      const float* __restrict__ W2, const float* __restrict__ b2,
                      float* __restrict__ out, int H, int HD) {
    int g = blockIdx.x;
    int t = threadIdx.x;
    float cnt = (float)gcnt[g];
    float inv = 1.0f / fmaxf(cnt, 1.0f);
    float hid = b1[t];
    for (int k = 0; k < H; ++k) {
        float gf = gsum[(size_t)g * H + k] * inv;
        hid = fmaf(gf, W1[k * HD + t], hid);
    }
    hid = fmaxf(hid, 0.f);
    float p = hid * W2[t];
    for (int off = 32; off > 0; off >>= 1) p += __shfl_down(p, off);
    if (t == 0) out[g] = p + b2[0];
}

// ---------------- host ----------------

extern "C" void kernel_launch(void* const* d_in, const int* in_sizes, int n_in,
                              void* d_out, int out_size, void* d_ws, size_t ws_size,
                              hipStream_t stream) {
    const float* x     = (const float*)d_in[0];
    const int*   ei    = (const int*)d_in[1];
    const int*   batch = (const int*)d_in[2];
    const float* convW = (const float*)d_in[3];
    const float* convb = (const float*)d_in[4];
    const float* gamma = (const float*)d_in[5];
    const float* beta  = (const float*)d_in[6];
    const float* mean  = (const float*)d_in[7];
    const float* var   = (const float*)d_in[8];
    const float* eW1   = (const float*)d_in[9];
    const float* eb1   = (const float*)d_in[10];
    const float* eW2   = (const float*)d_in[11];
    const float* eb2   = (const float*)d_in[12];
    const float* dW1   = (const float*)d_in[13];
    const float* db1   = (const float*)d_in[14];
    const float* dW2   = (const float*)d_in[15];
    const float* db2   = (const float*)d_in[16];

    int N  = in_sizes[0] / D;
    int E  = in_sizes[1] / 2;
    int L  = in_sizes[3] / (D * D);
    int G  = out_size;
    int LD = L * D;                 // 256
    int H1 = in_sizes[10];          // 256
    int H2 = in_sizes[12];          // 128
    int HD = in_sizes[14];          // 64

    char* ws = (char*)d_ws;
    size_t off = 0;
    auto alloc = [&](size_t b) -> void* {
        void* p = ws + off;
        off += (b + 255) & ~(size_t)255;
        return p;
    };
    float* local  = (float*)alloc((size_t)N * LD * 4);   // layer outputs; later reused as h2
    float* bufB   = (float*)alloc((size_t)N * LD * 4);   // xw then h1
    int*   csrc   = (int*)alloc((size_t)E * 4);
    float* dis    = (float*)alloc((size_t)N * 4);
    int*   indeg  = (int*)alloc((size_t)N * 4);
    int*   offs   = (int*)alloc((size_t)(N + 1) * 4);
    int*   cursor = (int*)alloc((size_t)N * 4);
    int nb = (N + 2047) / 2048;
    int*   bsum   = (int*)alloc((size_t)nb * 4);
    float* sc     = (float*)alloc((size_t)LD * 4);
    float* sh     = (float*)alloc((size_t)LD * 4);
    float* gsum   = (float*)alloc((size_t)G * H2 * 4);
    int*   gcnt   = (int*)alloc((size_t)G * 4);
    unsigned short* w1hi = (unsigned short*)alloc((size_t)LD * H1 * 2);
    unsigned short* w1lo = (unsigned short*)alloc((size_t)LD * H1 * 2);
    unsigned short* w2hi = (unsigned short*)alloc((size_t)H1 * H2 * 2);
    unsigned short* w2lo = (unsigned short*)alloc((size_t)H1 * H2 * 2);
    float* xw = bufB;
    float* h1 = bufB;
    float* h2 = local;

    hipMemsetAsync(indeg, 0, (size_t)N * 4, stream);
    hipMemsetAsync(cursor, 0, (size_t)N * 4, stream);
    hipMemsetAsync(gsum, 0, (size_t)G * H2 * 4, stream);
    hipMemsetAsync(gcnt, 0, (size_t)G * 4, stream);

    int tE = (E + 255) / 256;
    k_indeg<<<tE, 256, 0, stream>>>(ei + E, indeg, E);
    k_scan1<<<nb, 256, 0, stream>>>(indeg, bsum, N);
    k_scan2<<<1, 64, 0, stream>>>(bsum, nb, offs, N);
    k_scan3<<<nb, 256, 0, stream>>>(indeg, bsum, offs, N);
    k_dis<<<(N + 255) / 256, 256, 0, stream>>>(indeg, dis, N);
    k_bin<<<tE, 256, 0, stream>>>(ei, ei + E, offs, cursor, csrc, E);
    k_bnprep<<<(LD + 255) / 256, 256, 0, stream>>>(convb, gamma, beta, mean, var, sc, sh, LD);
    k_wsplit<<<(LD * H1 + 255) / 256, 256, 0, stream>>>(eW1, w1hi, w1lo, LD, H1, 8);
    k_wsplit<<<(H1 * H2 + 255) / 256, 256, 0, stream>>>(eW2, w2hi, w2lo, H1, H2, 7);

    for (int l = 0; l < L; ++l) {
        const float* Ain = (l == 0) ? x : (local + (size_t)(l - 1) * D);
        int lda = (l == 0) ? D : LD;
        k_conv<<<(N + 63) / 64, 256, 0, stream>>>(Ain, lda, convW + (size_t)l * D * D, dis, xw, N);
        const float* skip = (l % 2 == 0 && l != 0 && l != L - 1) ? (local + (size_t)(l - 2) * D) : nullptr;
        k_agg<<<(N + 15) / 16, 256, 0, stream>>>(xw, offs, csrc, dis, sc + (size_t)l * D,
                                                 sh + (size_t)l * D, skip,
                                                 local + (size_t)l * D, LD, N);
    }

    // enc1: NWN=4, BM=32; enc2: NWN=2, BM=64. LDS = 2 * 4 * PS * 16 bytes.
    {
        int BM = 32, PS = BM * 5 + 1;
        size_t shb = (size_t)2 * 4 * PS * 16;   // 20608 B
        k_encm<<<(N + BM - 1) / BM, 256, shb, stream>>>(local, LD, N, LD, w1hi, w1lo, eb1, h1, H1, 4);
    }
    {
        int BM = 64, PS = BM * 5 + 1;
        size_t shb = (size_t)2 * 4 * PS * 16;   // 41088 B
        k_encm<<<(N + BM - 1) / BM, 256, shb, stream>>>(h1, H1, N, H1, w2hi, w2lo, eb2, h2, H2, 2);
    }

    k_pool<<<(N + 511) / 512, H2, 0, stream>>>(h2, batch, gsum, gcnt, H2, N);
    k_dec<<<G, HD, 0, stream>>>(gsum, gcnt, dW1, db1, dW2, db2, (float*)d_out, H2, HD);
}

// Round 4
// 1112.226 us; speedup vs baseline: 1.2635x; 1.1814x over previous
//
#include <hip/hip_runtime.h>
#include <cstdint>
#include <cstddef>

#define D 64

typedef __attribute__((ext_vector_type(8))) short short8;
typedef __attribute__((ext_vector_type(4))) float floatx4;

// ---------------- bucket-partition CSR build ----------------
// bucket = col >> 8 (256 nodes per bucket). Pipeline:
//   k_hist: global bucket histogram (LDS-staged)
//   k_bscan: exclusive scan over buckets -> bstart, gcur; offs[N]=E
//   k_part: scatter (row,col) pairs bucket-major (per-block LDS reserve)
//   k_bucket: per-bucket node counts -> offs & dis; in-bucket bin -> csrc

__global__ void k_hist(const int* __restrict__ col, int* __restrict__ ghist,
                       int E, int NBK) {
    extern __shared__ int lh[];
    int t = threadIdx.x;
    for (int i = t; i < NBK; i += 256) lh[i] = 0;
    __syncthreads();
    int base = blockIdx.x * 8192;
    int end = base + 8192; if (end > E) end = E;
    for (int e = base + t; e < end; e += 256) atomicAdd(&lh[col[e] >> 8], 1);
    __syncthreads();
    for (int i = t; i < NBK; i += 256) if (lh[i]) atomicAdd(&ghist[i], lh[i]);
}

__global__ void k_bscan(const int* __restrict__ ghist, int* __restrict__ bstart,
                        int* __restrict__ gcur, int* __restrict__ offs,
                        int NBK, int N, int E) {
    __shared__ int s[512];
    int t = threadIdx.x;
    int v = (t < NBK) ? ghist[t] : 0;
    s[t] = v; __syncthreads();
    for (int off = 1; off < 512; off <<= 1) {
        int x = (t >= off) ? s[t - off] : 0;
        __syncthreads();
        s[t] += x;
        __syncthreads();
    }
    int excl = s[t] - v;
    if (t < NBK) { bstart[t] = excl; gcur[t] = excl; }
    if (t == 0) { bstart[NBK] = E; offs[N] = E; }
}

__global__ __launch_bounds__(256) void k_part(const int* __restrict__ row,
                                              const int* __restrict__ col,
                                              int* __restrict__ gcur,
                                              int2* __restrict__ part,
                                              int E, int NBK) {
    extern __shared__ int sm[];
    int* lcnt = sm;
    int* lbase = sm + NBK;
    int t = threadIdx.x;
    for (int i = t; i < NBK; i += 256) lcnt[i] = 0;
    __syncthreads();
    int base = blockIdx.x * 8192;
    int end = base + 8192; if (end > E) end = E;
    for (int e = base + t; e < end; e += 256) atomicAdd(&lcnt[col[e] >> 8], 1);
    __syncthreads();
    for (int i = t; i < NBK; i += 256) {
        int c = lcnt[i];
        lbase[i] = c ? atomicAdd(&gcur[i], c) : 0;
    }
    __syncthreads();
    for (int i = t; i < NBK; i += 256) lcnt[i] = 0;
    __syncthreads();
    for (int e = base + t; e < end; e += 256) {
        int c = col[e];
        int b = c >> 8;
        int p = lbase[b] + atomicAdd(&lcnt[b], 1);
        part[p] = make_int2(row[e], c);
    }
}

__global__ __launch_bounds__(256) void k_bucket(const int2* __restrict__ part,
                                                const int* __restrict__ bstart,
                                                int* __restrict__ offs,
                                                float* __restrict__ dis,
                                                int* __restrict__ csrc, int N) {
    __shared__ int ncnt[256];
    __shared__ int s[256];
    __shared__ int lcur[256];
    int b = blockIdx.x;
    int t = threadIdx.x;
    int n0 = b << 8;
    int e0 = bstart[b], e1 = bstart[b + 1];
    ncnt[t] = 0;
    __syncthreads();
    for (int e = e0 + t; e < e1; e += 256) {
        int2 pr = part[e];
        atomicAdd(&ncnt[pr.y & 255], 1);
    }
    __syncthreads();
    int v = ncnt[t];
    s[t] = v; __syncthreads();
    for (int off = 1; off < 256; off <<= 1) {
        int x = (t >= off) ? s[t - off] : 0;
        __syncthreads();
        s[t] += x;
        __syncthreads();
    }
    int excl = s[t] - v;
    int node = n0 + t;
    if (node < N) {
        offs[node] = e0 + excl;
        dis[node] = rsqrtf((float)(v + 1));
    }
    lcur[t] = excl;
    __syncthreads();
    for (int e = e0 + t; e < e1; e += 256) {
        int2 pr = part[e];
        int p = atomicAdd(&lcur[pr.y & 255], 1);
        csrc[e0 + p] = pr.x;
    }
}

// fold BN (eval) + conv bias into per-channel scale/shift
__global__ void k_bnprep(const float* __restrict__ cb, const float* __restrict__ g,
                         const float* __restrict__ be, const float* __restrict__ mu,
                         const float* __restrict__ var, float* __restrict__ sc,
                         float* __restrict__ sh, int LD) {
    int i = blockIdx.x * 256 + threadIdx.x;
    if (i < LD) {
        float s = g[i] * rsqrtf(var[i] + 1e-5f);
        sc[i] = s;
        sh[i] = (cb[i] - mu[i]) * s + be[i];
    }
}

// split fp32 weights into bf16 hi/lo, stored TRANSPOSED [n][k]
__global__ void k_wsplit(const float* __restrict__ B, unsigned short* __restrict__ hiT,
                         unsigned short* __restrict__ loT, int K, int Nc, int nshift) {
    int idx = blockIdx.x * 256 + threadIdx.x;
    if (idx >= K * Nc) return;
    int k = idx >> nshift;
    int n = idx & (Nc - 1);
    float a = B[idx];
    unsigned b = __float_as_uint(a);
    unsigned hb = b & 0xFFFF0000u;
    float ah = __uint_as_float(hb);
    float al = a - ah;
    hiT[(size_t)n * K + k] = (unsigned short)(hb >> 16);
    loT[(size_t)n * K + k] = (unsigned short)(__float_as_uint(al) >> 16);
}

// ---------------- conv GEMM: xw' = (A @ W) * dis[row],  K=D=64 ----------------

__global__ __launch_bounds__(256) void k_conv(const float* __restrict__ A, int lda,
                                              const float* __restrict__ W,
                                              const float* __restrict__ dis,
                                              float* __restrict__ out, int N) {
    __shared__ float At[64][68];
    __shared__ float Wl[64][64];
    int t = threadIdx.x;
    int bm = blockIdx.x * 64;
    {
        int row = t >> 2, kc = (t & 3) * 16;
        int r = bm + row;
        float v[16];
        if (r < N) {
            const float* p = A + (size_t)r * lda + kc;
#pragma unroll
            for (int j = 0; j < 16; j += 4) {
                float4 x = *(const float4*)(p + j);
                v[j] = x.x; v[j + 1] = x.y; v[j + 2] = x.z; v[j + 3] = x.w;
            }
        } else {
#pragma unroll
            for (int j = 0; j < 16; ++j) v[j] = 0.f;
        }
#pragma unroll
        for (int j = 0; j < 16; ++j) At[kc + j][row] = v[j];
        const float* wp = W + row * 64 + kc;
#pragma unroll
        for (int j = 0; j < 16; j += 4)
            *(float4*)&Wl[row][kc + j] = *(const float4*)(wp + j);
    }
    __syncthreads();
    int m0 = (t & 15) * 4, n0 = (t >> 4) * 4;
    float acc[4][4];
#pragma unroll
    for (int i = 0; i < 4; ++i)
#pragma unroll
        for (int j = 0; j < 4; ++j) acc[i][j] = 0.f;
#pragma unroll 8
    for (int kk = 0; kk < 64; ++kk) {
        float4 a = *(const float4*)&At[kk][m0];
        float4 b = *(const float4*)&Wl[kk][n0];
        float av[4] = {a.x, a.y, a.z, a.w};
        float bv[4] = {b.x, b.y, b.z, b.w};
#pragma unroll
        for (int i = 0; i < 4; ++i)
#pragma unroll
            for (int j = 0; j < 4; ++j) acc[i][j] = fmaf(av[i], bv[j], acc[i][j]);
    }
#pragma unroll
    for (int i = 0; i < 4; ++i) {
        int r = bm + m0 + i;
        if (r < N) {
            float dv = dis[r];
            float4 o;
            o.x = acc[i][0] * dv; o.y = acc[i][1] * dv;
            o.z = acc[i][2] * dv; o.w = acc[i][3] * dv;
            *(float4*)&out[(size_t)r * 64 + n0] = o;
        }
    }
}

// ---------------- aggregation: one node per wave, 4 edge slots x 16 chan lanes ----------------

__global__ __launch_bounds__(256) void k_agg(const float* __restrict__ xw,
                                             const int* __restrict__ offs,
                                             const int* __restrict__ src,
                                             const float* __restrict__ dis,
                                             const float* __restrict__ sc,
                                             const float* __restrict__ sh,
                                             const float* __restrict__ skip,
                                             float* __restrict__ out,
                                             int ld, int N) {
    int t = threadIdx.x;
    int lane = t & 63;
    int w = t >> 6;
    int v = blockIdx.x * 4 + w;
    if (v >= N) return;
    int es = lane >> 4;         // edge slot 0..3
    int f4 = lane & 15;         // float4 index within 64-float row
    int c0 = f4 * 4;
    const float* xp = xw + c0;
    float ax = 0.f, ay = 0.f, az = 0.f, aw_ = 0.f;
    int e0 = offs[v], e1 = offs[v + 1];
    int deg = e1 - e0;
    int k = 0;
    // main: 16 edges per iteration (4 per slot, indices broadcast via shfl)
    for (; k + 16 <= deg; k += 16) {
        int ld16 = (lane < 16) ? src[e0 + k + lane] : 0;
        int s0 = __shfl(ld16, es);
        int s1 = __shfl(ld16, es + 4);
        int s2 = __shfl(ld16, es + 8);
        int s3 = __shfl(ld16, es + 12);
        float4 m0 = *(const float4*)(xp + (size_t)s0 * 64);
        float4 m1 = *(const float4*)(xp + (size_t)s1 * 64);
        float4 m2 = *(const float4*)(xp + (size_t)s2 * 64);
        float4 m3 = *(const float4*)(xp + (size_t)s3 * 64);
        ax += (m0.x + m1.x) + (m2.x + m3.x);
        ay += (m0.y + m1.y) + (m2.y + m3.y);
        az += (m0.z + m1.z) + (m2.z + m3.z);
        aw_ += (m0.w + m1.w) + (m2.w + m3.w);
    }
    // 4 edges per iteration
    for (; k + 4 <= deg; k += 4) {
        int ld4 = (lane < 4) ? src[e0 + k + lane] : 0;
        int s0 = __shfl(ld4, es);
        float4 m0 = *(const float4*)(xp + (size_t)s0 * 64);
        ax += m0.x; ay += m0.y; az += m0.z; aw_ += m0.w;
    }
    // remainder 0..3 edges
    int rem = deg - k;
    if (es < rem) {
        int s0 = src[e0 + k + es];
        float4 m0 = *(const float4*)(xp + (size_t)s0 * 64);
        ax += m0.x; ay += m0.y; az += m0.z; aw_ += m0.w;
    }
    // reduce across the 4 edge slots
    ax += __shfl_xor(ax, 16); ay += __shfl_xor(ay, 16);
    az += __shfl_xor(az, 16); aw_ += __shfl_xor(aw_, 16);
    ax += __shfl_xor(ax, 32); ay += __shfl_xor(ay, 32);
    az += __shfl_xor(az, 32); aw_ += __shfl_xor(aw_, 32);
    if (es == 0) {
        // self loop (xw rows carry dis[src]; here src==v so it has dis[v] already)
        float4 a = *(const float4*)(xp + (size_t)v * 64);
        ax += a.x; ay += a.y; az += a.z; aw_ += a.w;
        float dv = dis[v];
        float4 S = *(const float4*)&sc[c0];
        float4 H = *(const float4*)&sh[c0];
        float y0 = fmaxf(fmaf(ax * dv, S.x, H.x), 0.f);
        float y1 = fmaxf(fmaf(ay * dv, S.y, H.y), 0.f);
        float y2 = fmaxf(fmaf(az * dv, S.z, H.z), 0.f);
        float y3 = fmaxf(fmaf(aw_ * dv, S.w, H.w), 0.f);
        size_t ob = (size_t)v * ld + c0;
        if (skip) {
            const float4 s4 = *(const float4*)(skip + ob);
            y0 += s4.x; y1 += s4.y; y2 += s4.z; y3 += s4.w;
        }
        float4 o; o.x = y0; o.y = y1; o.z = y2; o.w = y3;
        *(float4*)(out + ob) = o;
    }
}

// ---------------- encoder GEMM via bf16x3-split MFMA, LDS-staged A ----------------

__global__ __launch_bounds__(256) void k_encm(const float* __restrict__ A, int lda,
                                              int M, int K,
                                              const unsigned short* __restrict__ BhiT,
                                              const unsigned short* __restrict__ BloT,
                                              const float* __restrict__ bias,
                                              float* __restrict__ C, int ldc, int NWN) {
    extern __shared__ char smem[];
    const int BM = 128 / NWN;
    const int PS = BM * 5 + 1;
    short8* Ah = (short8*)smem;
    short8* Al = Ah + 4 * PS;

    int t = threadIdx.x;
    int lane = t & 63;
    int l16 = lane & 15;
    int quad = lane >> 4;
    int w = t >> 6;
    int nw = w % NWN;
    int mw = (w / NWN) * 32;
    int bm = blockIdx.x * BM;
    int n0 = nw * 64;

    floatx4 acc[2][4];
#pragma unroll
    for (int i = 0; i < 2; ++i)
#pragma unroll
        for (int j = 0; j < 4; ++j) acc[i][j] = (floatx4)0.f;

    const unsigned short* bp[4];
#pragma unroll
    for (int j = 0; j < 4; ++j)
        bp[j] = BhiT + (size_t)(n0 + j * 16 + l16) * K + quad * 8;
    size_t loOff = (size_t)(BloT - BhiT);

    const int ngroups = BM / 32;
    int grow = t >> 3;
    int c0 = (t & 7) * 16;

    for (int k0 = 0; k0 < K; k0 += 128) {
        if (k0) __syncthreads();
        for (int g = 0; g < ngroups; ++g) {
            int row = g * 32 + grow;
            int r = bm + row;
            float v[16];
            if (r < M) {
                const float* p = A + (size_t)r * lda + k0 + c0;
#pragma unroll
                for (int j = 0; j < 16; j += 4) {
                    float4 x = *(const float4*)(p + j);
                    v[j] = x.x; v[j + 1] = x.y; v[j + 2] = x.z; v[j + 3] = x.w;
                }
            } else {
#pragma unroll
                for (int j = 0; j < 16; ++j) v[j] = 0.f;
            }
#pragma unroll
            for (int q = 0; q < 2; ++q) {
                short8 hi, lo;
#pragma unroll
                for (int jj = 0; jj < 8; ++jj) {
                    float a = v[q * 8 + jj];
                    unsigned b = __float_as_uint(a);
                    unsigned hb = b & 0xFFFF0000u;
                    hi[jj] = (short)(hb >> 16);
                    float al = a - __uint_as_float(hb);
                    lo[jj] = (short)(__float_as_uint(al) >> 16);
                }
                int cc = c0 + q * 8;
                int u = (cc >> 5) * PS + row * 5 + ((cc & 31) >> 3);
                Ah[u] = hi;
                Al[u] = lo;
            }
        }
        __syncthreads();
#pragma unroll
        for (int kc = 0; kc < 4; ++kc) {
            int ub0 = kc * PS + (mw + l16) * 5 + quad;
            int ub1 = kc * PS + (mw + 16 + l16) * 5 + quad;
            short8 ah0 = Ah[ub0];
            short8 ah1 = Ah[ub1];
            short8 al0 = Al[ub0];
            short8 al1 = Al[ub1];
            int koff = k0 + kc * 32;
            short8 bh[4], bl[4];
#pragma unroll
            for (int j = 0; j < 4; ++j) {
                bh[j] = *(const short8*)(bp[j] + koff);
                bl[j] = *(const short8*)(bp[j] + loOff + koff);
            }
#pragma unroll
            for (int j = 0; j < 4; ++j) {
                acc[0][j] = __builtin_amdgcn_mfma_f32_16x16x32_bf16(al0, bh[j], acc[0][j], 0, 0, 0);
                acc[0][j] = __builtin_amdgcn_mfma_f32_16x16x32_bf16(ah0, bl[j], acc[0][j], 0, 0, 0);
                acc[0][j] = __builtin_amdgcn_mfma_f32_16x16x32_bf16(ah0, bh[j], acc[0][j], 0, 0, 0);
                acc[1][j] = __builtin_amdgcn_mfma_f32_16x16x32_bf16(al1, bh[j], acc[1][j], 0, 0, 0);
                acc[1][j] = __builtin_amdgcn_mfma_f32_16x16x32_bf16(ah1, bl[j], acc[1][j], 0, 0, 0);
                acc[1][j] = __builtin_amdgcn_mfma_f32_16x16x32_bf16(ah1, bh[j], acc[1][j], 0, 0, 0);
            }
        }
    }

#pragma unroll
    for (int i = 0; i < 2; ++i) {
#pragma unroll
        for (int r = 0; r < 4; ++r) {
            int m = bm + mw + i * 16 + quad * 4 + r;
            if (m < M) {
                float* cp = C + (size_t)m * ldc + n0 + l16;
#pragma unroll
                for (int j = 0; j < 4; ++j)
                    cp[j * 16] = fmaxf(acc[i][j][r] + bias[n0 + j * 16 + l16], 0.f);
            }
        }
    }
}

// ---------------- graph mean-pool ----------------

__global__ void k_pool(const float* __restrict__ h2, const int* __restrict__ batch,
                       float* __restrict__ gsum, int* __restrict__ gcnt, int H, int N) {
    int c = threadIdx.x;
    int n0 = blockIdx.x * 512;
    if (n0 >= N) return;
    int n1 = n0 + 512; if (n1 > N) n1 = N;
    float acc = 0.f;
    int cur = batch[n0];
    int cnt = 0;
    for (int n = n0; n < n1; ++n) {
        int g = batch[n];
        if (g != cur) {
            atomicAdd(&gsum[(size_t)cur * H + c], acc);
            if (c == 0) atomicAdd(&gcnt[cur], cnt);
            acc = 0.f; cnt = 0; cur = g;
        }
        acc += h2[(size_t)n * H + c];
        ++cnt;
    }
    atomicAdd(&gsum[(size_t)cur * H + c], acc);
    if (c == 0) atomicAdd(&gcnt[cur], cnt);
}

// ---------------- decoder ----------------

__global__ void k_dec(const float* __restrict__ gsum, const int* __restrict__ gcnt,
                      const float* __restrict__ W1, const float* __restrict__ b1,
                      const float* __restrict__ W2, const float* __restrict__ b2,
                      float* __restrict__ out, int H, int HD) {
    int g = blockIdx.x;
    int t = threadIdx.x;
    float cnt = (float)gcnt[g];
    float inv = 1.0f / fmaxf(cnt, 1.0f);
    float hid = b1[t];
    for (int k = 0; k < H; ++k) {
        float gf = gsum[(size_t)g * H + k] * inv;
        hid = fmaf(gf, W1[k * HD + t], hid);
    }
    hid = fmaxf(hid, 0.f);
    float p = hid * W2[t];
    for (int off = 32; off > 0; off >>= 1) p += __shfl_down(p, off);
    if (t == 0) out[g] = p + b2[0];
}

// ---------------- host ----------------

extern "C" void kernel_launch(void* const* d_in, const int* in_sizes, int n_in,
                              void* d_out, int out_size, void* d_ws, size_t ws_size,
                              hipStream_t stream) {
    const float* x     = (const float*)d_in[0];
    const int*   ei    = (const int*)d_in[1];
    const int*   batch = (const int*)d_in[2];
    const float* convW = (const float*)d_in[3];
    const float* convb = (const float*)d_in[4];
    const float* gamma = (const float*)d_in[5];
    const float* beta  = (const float*)d_in[6];
    const float* mean  = (const float*)d_in[7];
    const float* var   = (const float*)d_in[8];
    const float* eW1   = (const float*)d_in[9];
    const float* eb1   = (const float*)d_in[10];
    const float* eW2   = (const float*)d_in[11];
    const float* eb2   = (const float*)d_in[12];
    const float* dW1   = (const float*)d_in[13];
    const float* db1   = (const float*)d_in[14];
    const float* dW2   = (const float*)d_in[15];
    const float* db2   = (const float*)d_in[16];

    int N  = in_sizes[0] / D;
    int E  = in_sizes[1] / 2;
    int L  = in_sizes[3] / (D * D);
    int G  = out_size;
    int LD = L * D;                 // 256
    int H1 = in_sizes[10];          // 256
    int H2 = in_sizes[12];          // 128
    int HD = in_sizes[14];          // 64
    int NBK = (N + 255) >> 8;       // 391

    char* ws = (char*)d_ws;
    size_t off = 0;
    auto alloc = [&](size_t b) -> void* {
        void* p = ws + off;
        off += (b + 255) & ~(size_t)255;
        return p;
    };
    float* local  = (float*)alloc((size_t)N * LD * 4);   // layer outputs; later h2
    float* bufB   = (float*)alloc((size_t)N * LD * 4);   // part pairs, then xw, then h1
    int*   csrc   = (int*)alloc((size_t)E * 4);
    float* dis    = (float*)alloc((size_t)N * 4);
    int*   offs   = (int*)alloc((size_t)(N + 1) * 4);
    int*   ghist  = (int*)alloc((size_t)NBK * 4);
    int*   bstart = (int*)alloc((size_t)(NBK + 1) * 4);
    int*   gcur   = (int*)alloc((size_t)NBK * 4);
    float* sc     = (float*)alloc((size_t)LD * 4);
    float* sh     = (float*)alloc((size_t)LD * 4);
    float* gsum   = (float*)alloc((size_t)G * H2 * 4);
    int*   gcnt   = (int*)alloc((size_t)G * 4);
    unsigned short* w1hi = (unsigned short*)alloc((size_t)LD * H1 * 2);
    unsigned short* w1lo = (unsigned short*)alloc((size_t)LD * H1 * 2);
    unsigned short* w2hi = (unsigned short*)alloc((size_t)H1 * H2 * 2);
    unsigned short* w2lo = (unsigned short*)alloc((size_t)H1 * H2 * 2);
    int2* part = (int2*)bufB;        // aliases bufB; dead before first k_conv
    float* xw = bufB;
    float* h1 = bufB;
    float* h2 = local;

    hipMemsetAsync(ghist, 0, (size_t)NBK * 4, stream);
    hipMemsetAsync(gsum, 0, (size_t)G * H2 * 4, stream);
    hipMemsetAsync(gcnt, 0, (size_t)G * 4, stream);

    int nchunks = (E + 8191) / 8192;
    k_hist<<<nchunks, 256, NBK * 4, stream>>>(ei + E, ghist, E, NBK);
    k_bscan<<<1, 512, 0, stream>>>(ghist, bstart, gcur, offs, NBK, N, E);
    k_part<<<nchunks, 256, 2 * NBK * 4, stream>>>(ei, ei + E, gcur, part, E, NBK);
    k_bucket<<<NBK, 256, 0, stream>>>(part, bstart, offs, dis, csrc, N);
    k_bnprep<<<(LD + 255) / 256, 256, 0, stream>>>(convb, gamma, beta, mean, var, sc, sh, LD);
    k_wsplit<<<(LD * H1 + 255) / 256, 256, 0, stream>>>(eW1, w1hi, w1lo, LD, H1, 8);
    k_wsplit<<<(H1 * H2 + 255) / 256, 256, 0, stream>>>(eW2, w2hi, w2lo, H1, H2, 7);

    for (int l = 0; l < L; ++l) {
        const float* Ain = (l == 0) ? x : (local + (size_t)(l - 1) * D);
        int lda = (l == 0) ? D : LD;
        k_conv<<<(N + 63) / 64, 256, 0, stream>>>(Ain, lda, convW + (size_t)l * D * D, dis, xw, N);
        const float* skip = (l % 2 == 0 && l != 0 && l != L - 1) ? (local + (size_t)(l - 2) * D) : nullptr;
        k_agg<<<(N + 3) / 4, 256, 0, stream>>>(xw, offs, csrc, dis, sc + (size_t)l * D,
                                               sh + (size_t)l * D, skip,
                                               local + (size_t)l * D, LD, N);
    }

    {
        int BM = 32, PS = BM * 5 + 1;
        size_t shb = (size_t)2 * 4 * PS * 16;
        k_encm<<<(N + BM - 1) / BM, 256, shb, stream>>>(local, LD, N, LD, w1hi, w1lo, eb1, h1, H1, 4);
    }
    {
        int BM = 64, PS = BM * 5 + 1;
        size_t shb = (size_t)2 * 4 * PS * 16;
        k_encm<<<(N + BM - 1) / BM, 256, shb, stream>>>(h1, H1, N, H1, w2hi, w2lo, eb2, h2, H2, 2);
    }

    k_pool<<<(N + 511) / 512, H2, 0, stream>>>(h2, batch, gsum, gcnt, H2, N);
    k_dec<<<G, HD, 0, stream>>>(gsum, gcnt, dW1, db1, dW2, db2, (float*)d_out, H2, HD);
}

// Round 5
// 975.486 us; speedup vs baseline: 1.4406x; 1.1402x over previous
//
#include <hip/hip_runtime.h>
#include <cstdint>
#include <cstddef>

#define D 64
#define SMAX 24

typedef __attribute__((ext_vector_type(8))) short short8;
typedef __attribute__((ext_vector_type(4))) float floatx4;

// ---------------- bucket-partition CSR build ----------------
// bucket = col >> 8 (256 nodes per bucket). Pipeline:
//   k_hist: global bucket histogram (LDS-staged)
//   k_bscan: exclusive scan over buckets -> bstart, gcur; offs[N]=E
//   k_part: scatter (row,col) pairs bucket-major (per-block LDS reserve)
//   k_bucket: per-bucket node counts -> offs & dis; in-bucket bin -> csrc

__global__ void k_hist(const int* __restrict__ col, int* __restrict__ ghist,
                       int E, int NBK) {
    extern __shared__ int lh[];
    int t = threadIdx.x;
    for (int i = t; i < NBK; i += 256) lh[i] = 0;
    __syncthreads();
    int base = blockIdx.x * 8192;
    int end = base + 8192; if (end > E) end = E;
    for (int e = base + t; e < end; e += 256) atomicAdd(&lh[col[e] >> 8], 1);
    __syncthreads();
    for (int i = t; i < NBK; i += 256) if (lh[i]) atomicAdd(&ghist[i], lh[i]);
}

__global__ void k_bscan(const int* __restrict__ ghist, int* __restrict__ bstart,
                        int* __restrict__ gcur, int* __restrict__ offs,
                        int NBK, int N, int E) {
    __shared__ int s[512];
    int t = threadIdx.x;
    int v = (t < NBK) ? ghist[t] : 0;
    s[t] = v; __syncthreads();
    for (int off = 1; off < 512; off <<= 1) {
        int x = (t >= off) ? s[t - off] : 0;
        __syncthreads();
        s[t] += x;
        __syncthreads();
    }
    int excl = s[t] - v;
    if (t < NBK) { bstart[t] = excl; gcur[t] = excl; }
    if (t == 0) { bstart[NBK] = E; offs[N] = E; }
}

__global__ __launch_bounds__(256) void k_part(const int* __restrict__ row,
                                              const int* __restrict__ col,
                                              int* __restrict__ gcur,
                                              int2* __restrict__ part,
                                              int E, int NBK) {
    extern __shared__ int sm[];
    int* lcnt = sm;
    int* lbase = sm + NBK;
    int t = threadIdx.x;
    for (int i = t; i < NBK; i += 256) lcnt[i] = 0;
    __syncthreads();
    int base = blockIdx.x * 8192;
    int end = base + 8192; if (end > E) end = E;
    for (int e = base + t; e < end; e += 256) atomicAdd(&lcnt[col[e] >> 8], 1);
    __syncthreads();
    for (int i = t; i < NBK; i += 256) {
        int c = lcnt[i];
        lbase[i] = c ? atomicAdd(&gcur[i], c) : 0;
    }
    __syncthreads();
    for (int i = t; i < NBK; i += 256) lcnt[i] = 0;
    __syncthreads();
    for (int e = base + t; e < end; e += 256) {
        int c = col[e];
        int b = c >> 8;
        int p = lbase[b] + atomicAdd(&lcnt[b], 1);
        part[p] = make_int2(row[e], c);
    }
}

__global__ __launch_bounds__(256) void k_bucket(const int2* __restrict__ part,
                                                const int* __restrict__ bstart,
                                                int* __restrict__ offs,
                                                float* __restrict__ dis,
                                                int* __restrict__ csrc, int N) {
    __shared__ int ncnt[256];
    __shared__ int s[256];
    __shared__ int lcur[256];
    int b = blockIdx.x;
    int t = threadIdx.x;
    int n0 = b << 8;
    int e0 = bstart[b], e1 = bstart[b + 1];
    ncnt[t] = 0;
    __syncthreads();
    for (int e = e0 + t; e < e1; e += 256) {
        int2 pr = part[e];
        atomicAdd(&ncnt[pr.y & 255], 1);
    }
    __syncthreads();
    int v = ncnt[t];
    s[t] = v; __syncthreads();
    for (int off = 1; off < 256; off <<= 1) {
        int x = (t >= off) ? s[t - off] : 0;
        __syncthreads();
        s[t] += x;
        __syncthreads();
    }
    int excl = s[t] - v;
    int node = n0 + t;
    if (node < N) {
        offs[node] = e0 + excl;
        dis[node] = rsqrtf((float)(v + 1));
    }
    lcur[t] = excl;
    __syncthreads();
    for (int e = e0 + t; e < e1; e += 256) {
        int2 pr = part[e];
        int p = atomicAdd(&lcur[pr.y & 255], 1);
        csrc[e0 + p] = pr.x;
    }
}

// graph boundaries: gstart[g] = lower_bound(batch, g); gstart[G] = N
__global__ void k_gb(const int* __restrict__ batch, int* __restrict__ gstart,
                     int N, int G) {
    int g = threadIdx.x;
    if (g > G) return;
    int lo = 0, hi = N;
    while (lo < hi) {
        int mid = (lo + hi) >> 1;
        if (batch[mid] < g) lo = mid + 1; else hi = mid;
    }
    gstart[g] = lo;
}

// fold BN (eval) + conv bias into per-channel scale/shift
__global__ void k_bnprep(const float* __restrict__ cb, const float* __restrict__ g,
                         const float* __restrict__ be, const float* __restrict__ mu,
                         const float* __restrict__ var, float* __restrict__ sc,
                         float* __restrict__ sh, int LD) {
    int i = blockIdx.x * 256 + threadIdx.x;
    if (i < LD) {
        float s = g[i] * rsqrtf(var[i] + 1e-5f);
        sc[i] = s;
        sh[i] = (cb[i] - mu[i]) * s + be[i];
    }
}

// split fp32 weights into bf16 hi/lo, stored TRANSPOSED [n][k]
__global__ void k_wsplit(const float* __restrict__ B, unsigned short* __restrict__ hiT,
                         unsigned short* __restrict__ loT, int K, int Nc, int nshift) {
    int idx = blockIdx.x * 256 + threadIdx.x;
    if (idx >= K * Nc) return;
    int k = idx >> nshift;
    int n = idx & (Nc - 1);
    float a = B[idx];
    unsigned b = __float_as_uint(a);
    unsigned hb = b & 0xFFFF0000u;
    float ah = __uint_as_float(hb);
    float al = a - ah;
    hiT[(size_t)n * K + k] = (unsigned short)(hb >> 16);
    loT[(size_t)n * K + k] = (unsigned short)(__float_as_uint(al) >> 16);
}

// ---------------- conv GEMM: xw' = (A @ W) * dis[row],  K=D=64 ----------------

__global__ __launch_bounds__(256) void k_conv(const float* __restrict__ A, int lda,
                                              const float* __restrict__ W,
                                              const float* __restrict__ dis,
                                              float* __restrict__ out, int N) {
    __shared__ float At[64][68];
    __shared__ float Wl[64][64];
    int t = threadIdx.x;
    int bm = blockIdx.x * 64;
    {
        int row = t >> 2, kc = (t & 3) * 16;
        int r = bm + row;
        float v[16];
        if (r < N) {
            const float* p = A + (size_t)r * lda + kc;
#pragma unroll
            for (int j = 0; j < 16; j += 4) {
                float4 x = *(const float4*)(p + j);
                v[j] = x.x; v[j + 1] = x.y; v[j + 2] = x.z; v[j + 3] = x.w;
            }
        } else {
#pragma unroll
            for (int j = 0; j < 16; ++j) v[j] = 0.f;
        }
#pragma unroll
        for (int j = 0; j < 16; ++j) At[kc + j][row] = v[j];
        const float* wp = W + row * 64 + kc;
#pragma unroll
        for (int j = 0; j < 16; j += 4)
            *(float4*)&Wl[row][kc + j] = *(const float4*)(wp + j);
    }
    __syncthreads();
    int m0 = (t & 15) * 4, n0 = (t >> 4) * 4;
    float acc[4][4];
#pragma unroll
    for (int i = 0; i < 4; ++i)
#pragma unroll
        for (int j = 0; j < 4; ++j) acc[i][j] = 0.f;
#pragma unroll 8
    for (int kk = 0; kk < 64; ++kk) {
        float4 a = *(const float4*)&At[kk][m0];
        float4 b = *(const float4*)&Wl[kk][n0];
        float av[4] = {a.x, a.y, a.z, a.w};
        float bv[4] = {b.x, b.y, b.z, b.w};
#pragma unroll
        for (int i = 0; i < 4; ++i)
#pragma unroll
            for (int j = 0; j < 4; ++j) acc[i][j] = fmaf(av[i], bv[j], acc[i][j]);
    }
#pragma unroll
    for (int i = 0; i < 4; ++i) {
        int r = bm + m0 + i;
        if (r < N) {
            float dv = dis[r];
            float4 o;
            o.x = acc[i][0] * dv; o.y = acc[i][1] * dv;
            o.z = acc[i][2] * dv; o.w = acc[i][3] * dv;
            *(float4*)&out[(size_t)r * 64 + n0] = o;
        }
    }
}

// ---------------- aggregation: one node per wave, 4 edge slots x 16 chan lanes ----------------

__global__ __launch_bounds__(256) void k_agg(const float* __restrict__ xw,
                                             const int* __restrict__ offs,
                                             const int* __restrict__ src,
                                             const float* __restrict__ dis,
                                             const float* __restrict__ sc,
                                             const float* __restrict__ sh,
                                             const float* __restrict__ skip,
                                             float* __restrict__ out,
                                             int ld, int N) {
    int t = threadIdx.x;
    int lane = t & 63;
    int w = t >> 6;
    int v = blockIdx.x * 4 + w;
    if (v >= N) return;
    int es = lane >> 4;         // edge slot 0..3
    int f4 = lane & 15;         // float4 index within 64-float row
    int c0 = f4 * 4;
    const float* xp = xw + c0;
    float ax = 0.f, ay = 0.f, az = 0.f, aw_ = 0.f;
    int e0 = offs[v], e1 = offs[v + 1];
    int deg = e1 - e0;
    int k = 0;
    for (; k + 16 <= deg; k += 16) {
        int ld16 = (lane < 16) ? src[e0 + k + lane] : 0;
        int s0 = __shfl(ld16, es);
        int s1 = __shfl(ld16, es + 4);
        int s2 = __shfl(ld16, es + 8);
        int s3 = __shfl(ld16, es + 12);
        float4 m0 = *(const float4*)(xp + (size_t)s0 * 64);
        float4 m1 = *(const float4*)(xp + (size_t)s1 * 64);
        float4 m2 = *(const float4*)(xp + (size_t)s2 * 64);
        float4 m3 = *(const float4*)(xp + (size_t)s3 * 64);
        ax += (m0.x + m1.x) + (m2.x + m3.x);
        ay += (m0.y + m1.y) + (m2.y + m3.y);
        az += (m0.z + m1.z) + (m2.z + m3.z);
        aw_ += (m0.w + m1.w) + (m2.w + m3.w);
    }
    for (; k + 4 <= deg; k += 4) {
        int ld4 = (lane < 4) ? src[e0 + k + lane] : 0;
        int s0 = __shfl(ld4, es);
        float4 m0 = *(const float4*)(xp + (size_t)s0 * 64);
        ax += m0.x; ay += m0.y; az += m0.z; aw_ += m0.w;
    }
    int rem = deg - k;
    if (es < rem) {
        int s0 = src[e0 + k + es];
        float4 m0 = *(const float4*)(xp + (size_t)s0 * 64);
        ax += m0.x; ay += m0.y; az += m0.z; aw_ += m0.w;
    }
    ax += __shfl_xor(ax, 16); ay += __shfl_xor(ay, 16);
    az += __shfl_xor(az, 16); aw_ += __shfl_xor(aw_, 16);
    ax += __shfl_xor(ax, 32); ay += __shfl_xor(ay, 32);
    az += __shfl_xor(az, 32); aw_ += __shfl_xor(aw_, 32);
    if (es == 0) {
        float4 a = *(const float4*)(xp + (size_t)v * 64);
        ax += a.x; ay += a.y; az += a.z; aw_ += a.w;
        float dv = dis[v];
        float4 S = *(const float4*)&sc[c0];
        float4 H = *(const float4*)&sh[c0];
        float y0 = fmaxf(fmaf(ax * dv, S.x, H.x), 0.f);
        float y1 = fmaxf(fmaf(ay * dv, S.y, H.y), 0.f);
        float y2 = fmaxf(fmaf(az * dv, S.z, H.z), 0.f);
        float y3 = fmaxf(fmaf(aw_ * dv, S.w, H.w), 0.f);
        size_t ob = (size_t)v * ld + c0;
        if (skip) {
            const float4 s4 = *(const float4*)(skip + ob);
            y0 += s4.x; y1 += s4.y; y2 += s4.z; y3 += s4.w;
        }
        float4 o; o.x = y0; o.y = y1; o.z = y2; o.w = y3;
        *(float4*)(out + ob) = o;
    }
}

// ---------------- encoder GEMM via bf16x3-split MFMA, LDS-staged A ----------------

__global__ __launch_bounds__(256) void k_encm(const float* __restrict__ A, int lda,
                                              int M, int K,
                                              const unsigned short* __restrict__ BhiT,
                                              const unsigned short* __restrict__ BloT,
                                              const float* __restrict__ bias,
                                              float* __restrict__ C, int ldc, int NWN) {
    extern __shared__ char smem[];
    const int BM = 128 / NWN;
    const int PS = BM * 5 + 1;
    short8* Ah = (short8*)smem;
    short8* Al = Ah + 4 * PS;

    int t = threadIdx.x;
    int lane = t & 63;
    int l16 = lane & 15;
    int quad = lane >> 4;
    int w = t >> 6;
    int nw = w % NWN;
    int mw = (w / NWN) * 32;
    int bm = blockIdx.x * BM;
    int n0 = nw * 64;

    floatx4 acc[2][4];
#pragma unroll
    for (int i = 0; i < 2; ++i)
#pragma unroll
        for (int j = 0; j < 4; ++j) acc[i][j] = (floatx4)0.f;

    const unsigned short* bp[4];
#pragma unroll
    for (int j = 0; j < 4; ++j)
        bp[j] = BhiT + (size_t)(n0 + j * 16 + l16) * K + quad * 8;
    size_t loOff = (size_t)(BloT - BhiT);

    const int ngroups = BM / 32;
    int grow = t >> 3;
    int c0 = (t & 7) * 16;

    for (int k0 = 0; k0 < K; k0 += 128) {
        if (k0) __syncthreads();
        for (int g = 0; g < ngroups; ++g) {
            int row = g * 32 + grow;
            int r = bm + row;
            float v[16];
            if (r < M) {
                const float* p = A + (size_t)r * lda + k0 + c0;
#pragma unroll
                for (int j = 0; j < 16; j += 4) {
                    float4 x = *(const float4*)(p + j);
                    v[j] = x.x; v[j + 1] = x.y; v[j + 2] = x.z; v[j + 3] = x.w;
                }
            } else {
#pragma unroll
                for (int j = 0; j < 16; ++j) v[j] = 0.f;
            }
#pragma unroll
            for (int q = 0; q < 2; ++q) {
                short8 hi, lo;
#pragma unroll
                for (int jj = 0; jj < 8; ++jj) {
                    float a = v[q * 8 + jj];
                    unsigned b = __float_as_uint(a);
                    unsigned hb = b & 0xFFFF0000u;
                    hi[jj] = (short)(hb >> 16);
                    float al = a - __uint_as_float(hb);
                    lo[jj] = (short)(__float_as_uint(al) >> 16);
                }
                int cc = c0 + q * 8;
                int u = (cc >> 5) * PS + row * 5 + ((cc & 31) >> 3);
                Ah[u] = hi;
                Al[u] = lo;
            }
        }
        __syncthreads();
#pragma unroll
        for (int kc = 0; kc < 4; ++kc) {
            int ub0 = kc * PS + (mw + l16) * 5 + quad;
            int ub1 = kc * PS + (mw + 16 + l16) * 5 + quad;
            short8 ah0 = Ah[ub0];
            short8 ah1 = Ah[ub1];
            short8 al0 = Al[ub0];
            short8 al1 = Al[ub1];
            int koff = k0 + kc * 32;
            short8 bh[4], bl[4];
#pragma unroll
            for (int j = 0; j < 4; ++j) {
                bh[j] = *(const short8*)(bp[j] + koff);
                bl[j] = *(const short8*)(bp[j] + loOff + koff);
            }
#pragma unroll
            for (int j = 0; j < 4; ++j) {
                acc[0][j] = __builtin_amdgcn_mfma_f32_16x16x32_bf16(al0, bh[j], acc[0][j], 0, 0, 0);
                acc[0][j] = __builtin_amdgcn_mfma_f32_16x16x32_bf16(ah0, bl[j], acc[0][j], 0, 0, 0);
                acc[0][j] = __builtin_amdgcn_mfma_f32_16x16x32_bf16(ah0, bh[j], acc[0][j], 0, 0, 0);
                acc[1][j] = __builtin_amdgcn_mfma_f32_16x16x32_bf16(al1, bh[j], acc[1][j], 0, 0, 0);
                acc[1][j] = __builtin_amdgcn_mfma_f32_16x16x32_bf16(ah1, bl[j], acc[1][j], 0, 0, 0);
                acc[1][j] = __builtin_amdgcn_mfma_f32_16x16x32_bf16(ah1, bh[j], acc[1][j], 0, 0, 0);
            }
        }
    }

#pragma unroll
    for (int i = 0; i < 2; ++i) {
#pragma unroll
        for (int r = 0; r < 4; ++r) {
            int m = bm + mw + i * 16 + quad * 4 + r;
            if (m < M) {
                float* cp = C + (size_t)m * ldc + n0 + l16;
#pragma unroll
                for (int j = 0; j < 4; ++j)
                    cp[j * 16] = fmaxf(acc[i][j][r] + bias[n0 + j * 16 + l16], 0.f);
            }
        }
    }
}

// ---------------- graph mean-pool: G x SMAX slice blocks, coalesced float4 ----------------

__global__ __launch_bounds__(256) void k_pool(const float* __restrict__ h2,
                                              const int* __restrict__ gstart,
                                              float* __restrict__ gsum, int H) {
    int g = blockIdx.x / SMAX;
    int s = blockIdx.x % SMAX;
    int base = gstart[g], end = gstart[g + 1];
    int cnt = end - base;
    if (cnt <= 0) return;
    int per = (cnt + SMAX - 1) / SMAX;
    int n0 = base + s * per;
    int n1 = n0 + per; if (n1 > end) n1 = end;
    if (n0 >= n1) return;
    int t = threadIdx.x;
    int q = t & 31;            // channel quad (H=128 -> 32 quads)
    int c = q * 4;
    int sub = t >> 5;          // 0..7 node sub-stream
    float4 acc = make_float4(0.f, 0.f, 0.f, 0.f);
    for (int n = n0 + sub; n < n1; n += 8) {
        float4 v = *(const float4*)(h2 + (size_t)n * H + c);
        acc.x += v.x; acc.y += v.y; acc.z += v.z; acc.w += v.w;
    }
    __shared__ float4 red[8][32];
    red[sub][q] = acc;
    __syncthreads();
    if (sub == 0) {
        float4 a = red[0][q];
#pragma unroll
        for (int i = 1; i < 8; ++i) {
            float4 b = red[i][q];
            a.x += b.x; a.y += b.y; a.z += b.z; a.w += b.w;
        }
        atomicAdd(&gsum[(size_t)g * H + c + 0], a.x);
        atomicAdd(&gsum[(size_t)g * H + c + 1], a.y);
        atomicAdd(&gsum[(size_t)g * H + c + 2], a.z);
        atomicAdd(&gsum[(size_t)g * H + c + 3], a.w);
    }
}

// ---------------- decoder ----------------

__global__ void k_dec(const float* __restrict__ gsum, const int* __restrict__ gstart,
                      const float* __restrict__ W1, const float* __restrict__ b1,
                      const float* __restrict__ W2, const float* __restrict__ b2,
                      float* __restrict__ out, int H, int HD) {
    int g = blockIdx.x;
    int t = threadIdx.x;
    float cnt = (float)(gstart[g + 1] - gstart[g]);
    float inv = 1.0f / fmaxf(cnt, 1.0f);
    float hid = b1[t];
    for (int k = 0; k < H; ++k) {
        float gf = gsum[(size_t)g * H + k] * inv;
        hid = fmaf(gf, W1[k * HD + t], hid);
    }
    hid = fmaxf(hid, 0.f);
    float p = hid * W2[t];
    for (int off = 32; off > 0; off >>= 1) p += __shfl_down(p, off);
    if (t == 0) out[g] = p + b2[0];
}

// ---------------- host ----------------

extern "C" void kernel_launch(void* const* d_in, const int* in_sizes, int n_in,
                              void* d_out, int out_size, void* d_ws, size_t ws_size,
                              hipStream_t stream) {
    const float* x     = (const float*)d_in[0];
    const int*   ei    = (const int*)d_in[1];
    const int*   batch = (const int*)d_in[2];
    const float* convW = (const float*)d_in[3];
    const float* convb = (const float*)d_in[4];
    const float* gamma = (const float*)d_in[5];
    const float* beta  = (const float*)d_in[6];
    const float* mean  = (const float*)d_in[7];
    const float* var   = (const float*)d_in[8];
    const float* eW1   = (const float*)d_in[9];
    const float* eb1   = (const float*)d_in[10];
    const float* eW2   = (const float*)d_in[11];
    const float* eb2   = (const float*)d_in[12];
    const float* dW1   = (const float*)d_in[13];
    const float* db1   = (const float*)d_in[14];
    const float* dW2   = (const float*)d_in[15];
    const float* db2   = (const float*)d_in[16];

    int N  = in_sizes[0] / D;
    int E  = in_sizes[1] / 2;
    int L  = in_sizes[3] / (D * D);
    int G  = out_size;
    int LD = L * D;                 // 256
    int H1 = in_sizes[10];          // 256
    int H2 = in_sizes[12];          // 128
    int HD = in_sizes[14];          // 64
    int NBK = (N + 255) >> 8;       // 391

    char* ws = (char*)d_ws;
    size_t off = 0;
    auto alloc = [&](size_t b) -> void* {
        void* p = ws + off;
        off += (b + 255) & ~(size_t)255;
        return p;
    };
    float* local  = (float*)alloc((size_t)N * LD * 4);   // layer outputs; later h2
    float* bufB   = (float*)alloc((size_t)N * LD * 4);   // part pairs, then xw, then h1
    int*   csrc   = (int*)alloc((size_t)E * 4);
    float* dis    = (float*)alloc((size_t)N * 4);
    int*   offs   = (int*)alloc((size_t)(N + 1) * 4);
    int*   ghist  = (int*)alloc((size_t)NBK * 4);
    int*   bstart = (int*)alloc((size_t)(NBK + 1) * 4);
    int*   gcur   = (int*)alloc((size_t)NBK * 4);
    float* sc     = (float*)alloc((size_t)LD * 4);
    float* sh     = (float*)alloc((size_t)LD * 4);
    float* gsum   = (float*)alloc((size_t)G * H2 * 4);
    int*   gstart = (int*)alloc((size_t)(G + 1) * 4);
    unsigned short* w1hi = (unsigned short*)alloc((size_t)LD * H1 * 2);
    unsigned short* w1lo = (unsigned short*)alloc((size_t)LD * H1 * 2);
    unsigned short* w2hi = (unsigned short*)alloc((size_t)H1 * H2 * 2);
    unsigned short* w2lo = (unsigned short*)alloc((size_t)H1 * H2 * 2);
    int2* part = (int2*)bufB;        // aliases bufB; dead before first k_conv
    float* xw = bufB;
    float* h1 = bufB;
    float* h2 = local;

    hipMemsetAsync(ghist, 0, (size_t)NBK * 4, stream);
    hipMemsetAsync(gsum, 0, (size_t)G * H2 * 4, stream);

    int nchunks = (E + 8191) / 8192;
    k_hist<<<nchunks, 256, NBK * 4, stream>>>(ei + E, ghist, E, NBK);
    k_bscan<<<1, 512, 0, stream>>>(ghist, bstart, gcur, offs, NBK, N, E);
    k_part<<<nchunks, 256, 2 * NBK * 4, stream>>>(ei, ei + E, gcur, part, E, NBK);
    k_bucket<<<NBK, 256, 0, stream>>>(part, bstart, offs, dis, csrc, N);
    k_gb<<<1, 128, 0, stream>>>(batch, gstart, N, G);
    k_bnprep<<<(LD + 255) / 256, 256, 0, stream>>>(convb, gamma, beta, mean, var, sc, sh, LD);
    k_wsplit<<<(LD * H1 + 255) / 256, 256, 0, stream>>>(eW1, w1hi, w1lo, LD, H1, 8);
    k_wsplit<<<(H1 * H2 + 255) / 256, 256, 0, stream>>>(eW2, w2hi, w2lo, H1, H2, 7);

    for (int l = 0; l < L; ++l) {
        const float* Ain = (l == 0) ? x : (local + (size_t)(l - 1) * D);
        int lda = (l == 0) ? D : LD;
        k_conv<<<(N + 63) / 64, 256, 0, stream>>>(Ain, lda, convW + (size_t)l * D * D, dis, xw, N);
        const float* skip = (l % 2 == 0 && l != 0 && l != L - 1) ? (local + (size_t)(l - 2) * D) : nullptr;
        k_agg<<<(N + 3) / 4, 256, 0, stream>>>(xw, offs, csrc, dis, sc + (size_t)l * D,
                                               sh + (size_t)l * D, skip,
                                               local + (size_t)l * D, LD, N);
    }

    {
        int BM = 32, PS = BM * 5 + 1;
        size_t shb = (size_t)2 * 4 * PS * 16;
        k_encm<<<(N + BM - 1) / BM, 256, shb, stream>>>(local, LD, N, LD, w1hi, w1lo, eb1, h1, H1, 4);
    }
    {
        int BM = 64, PS = BM * 5 + 1;
        size_t shb = (size_t)2 * 4 * PS * 16;
        k_encm<<<(N + BM - 1) / BM, 256, shb, stream>>>(h1, H1, N, H1, w2hi, w2lo, eb2, h2, H2, 2);
    }

    k_pool<<<G * SMAX, 256, 0, stream>>>(h2, gstart, gsum, H2);
    k_dec<<<G, HD, 0, stream>>>(gsum, gstart, dW1, db1, dW2, db2, (float*)d_out, H2, HD);
}

// Round 6
// 813.964 us; speedup vs baseline: 1.7265x; 1.1984x over previous
//
#include <hip/hip_runtime.h>
#include <cstdint>
#include <cstddef>

#define D 64
#define SMAX 24

typedef __attribute__((ext_vector_type(8))) short short8;
typedef __attribute__((ext_vector_type(4))) float floatx4;

__device__ inline unsigned short f2bf(float f) {   // RNE fp32 -> bf16
    unsigned u = __float_as_uint(f);
    unsigned r = 0x7FFFu + ((u >> 16) & 1u);
    return (unsigned short)((u + r) >> 16);
}
__device__ inline float bf2f(unsigned short h) {
    return __uint_as_float(((unsigned)h) << 16);
}

// ---------------- bucket-partition CSR build ----------------

__global__ void k_hist(const int* __restrict__ col, int* __restrict__ ghist,
                       int E, int NBK) {
    extern __shared__ int lh[];
    int t = threadIdx.x;
    for (int i = t; i < NBK; i += 256) lh[i] = 0;
    __syncthreads();
    int base = blockIdx.x * 8192;
    int end = base + 8192; if (end > E) end = E;
    for (int e = base + t; e < end; e += 256) atomicAdd(&lh[col[e] >> 8], 1);
    __syncthreads();
    for (int i = t; i < NBK; i += 256) if (lh[i]) atomicAdd(&ghist[i], lh[i]);
}

__global__ void k_bscan(const int* __restrict__ ghist, int* __restrict__ bstart,
                        int* __restrict__ gcur, int* __restrict__ offs,
                        int NBK, int N, int E) {
    __shared__ int s[512];
    int t = threadIdx.x;
    int v = (t < NBK) ? ghist[t] : 0;
    s[t] = v; __syncthreads();
    for (int off = 1; off < 512; off <<= 1) {
        int x = (t >= off) ? s[t - off] : 0;
        __syncthreads();
        s[t] += x;
        __syncthreads();
    }
    int excl = s[t] - v;
    if (t < NBK) { bstart[t] = excl; gcur[t] = excl; }
    if (t == 0) { bstart[NBK] = E; offs[N] = E; }
}

__global__ __launch_bounds__(256) void k_part(const int* __restrict__ row,
                                              const int* __restrict__ col,
                                              int* __restrict__ gcur,
                                              int2* __restrict__ part,
                                              int E, int NBK) {
    extern __shared__ int sm[];
    int* lcnt = sm;
    int* lbase = sm + NBK;
    int t = threadIdx.x;
    for (int i = t; i < NBK; i += 256) lcnt[i] = 0;
    __syncthreads();
    int base = blockIdx.x * 8192;
    int end = base + 8192; if (end > E) end = E;
    for (int e = base + t; e < end; e += 256) atomicAdd(&lcnt[col[e] >> 8], 1);
    __syncthreads();
    for (int i = t; i < NBK; i += 256) {
        int c = lcnt[i];
        lbase[i] = c ? atomicAdd(&gcur[i], c) : 0;
    }
    __syncthreads();
    for (int i = t; i < NBK; i += 256) lcnt[i] = 0;
    __syncthreads();
    for (int e = base + t; e < end; e += 256) {
        int c = col[e];
        int b = c >> 8;
        int p = lbase[b] + atomicAdd(&lcnt[b], 1);
        part[p] = make_int2(row[e], c);
    }
}

__global__ __launch_bounds__(256) void k_bucket(const int2* __restrict__ part,
                                                const int* __restrict__ bstart,
                                                int* __restrict__ offs,
                                                float* __restrict__ dis,
                                                int* __restrict__ csrc, int N) {
    __shared__ int ncnt[256];
    __shared__ int s[256];
    __shared__ int lcur[256];
    int b = blockIdx.x;
    int t = threadIdx.x;
    int n0 = b << 8;
    int e0 = bstart[b], e1 = bstart[b + 1];
    ncnt[t] = 0;
    __syncthreads();
    for (int e = e0 + t; e < e1; e += 256) {
        int2 pr = part[e];
        atomicAdd(&ncnt[pr.y & 255], 1);
    }
    __syncthreads();
    int v = ncnt[t];
    s[t] = v; __syncthreads();
    for (int off = 1; off < 256; off <<= 1) {
        int x = (t >= off) ? s[t - off] : 0;
        __syncthreads();
        s[t] += x;
        __syncthreads();
    }
    int excl = s[t] - v;
    int node = n0 + t;
    if (node < N) {
        offs[node] = e0 + excl;
        dis[node] = rsqrtf((float)(v + 1));
    }
    lcur[t] = excl;
    __syncthreads();
    for (int e = e0 + t; e < e1; e += 256) {
        int2 pr = part[e];
        int p = atomicAdd(&lcur[pr.y & 255], 1);
        csrc[e0 + p] = pr.x;
    }
}

// graph boundaries
__global__ void k_gb(const int* __restrict__ batch, int* __restrict__ gstart,
                     int N, int G) {
    int g = threadIdx.x;
    if (g > G) return;
    int lo = 0, hi = N;
    while (lo < hi) {
        int mid = (lo + hi) >> 1;
        if (batch[mid] < g) lo = mid + 1; else hi = mid;
    }
    gstart[g] = lo;
}

// fold BN (eval) + conv bias into per-channel scale/shift
__global__ void k_bnprep(const float* __restrict__ cb, const float* __restrict__ g,
                         const float* __restrict__ be, const float* __restrict__ mu,
                         const float* __restrict__ var, float* __restrict__ sc,
                         float* __restrict__ sh, int LD) {
    int i = blockIdx.x * 256 + threadIdx.x;
    if (i < LD) {
        float s = g[i] * rsqrtf(var[i] + 1e-5f);
        sc[i] = s;
        sh[i] = (cb[i] - mu[i]) * s + be[i];
    }
}

// split fp32 weights into bf16 hi/lo, stored TRANSPOSED [n][k]
__global__ void k_wsplit(const float* __restrict__ B, unsigned short* __restrict__ hiT,
                         unsigned short* __restrict__ loT, int K, int Nc, int nshift) {
    int idx = blockIdx.x * 256 + threadIdx.x;
    if (idx >= K * Nc) return;
    int k = idx >> nshift;
    int n = idx & (Nc - 1);
    float a = B[idx];
    unsigned b = __float_as_uint(a);
    unsigned hb = b & 0xFFFF0000u;
    float ah = __uint_as_float(hb);
    float al = a - ah;
    hiT[(size_t)n * K + k] = (unsigned short)(hb >> 16);
    loT[(size_t)n * K + k] = (unsigned short)(__float_as_uint(al) >> 16);
}

// ---------------- conv GEMM: xw' = bf16((A @ W) * dis[row]),  K=D=64 ----------------

__global__ __launch_bounds__(256) void k_conv(const float* __restrict__ A, int lda,
                                              const float* __restrict__ W,
                                              const float* __restrict__ dis,
                                              unsigned short* __restrict__ out, int N) {
    __shared__ float At[64][68];
    __shared__ float Wl[64][64];
    int t = threadIdx.x;
    int bm = blockIdx.x * 64;
    {
        int row = t >> 2, kc = (t & 3) * 16;
        int r = bm + row;
        float v[16];
        if (r < N) {
            const float* p = A + (size_t)r * lda + kc;
#pragma unroll
            for (int j = 0; j < 16; j += 4) {
                float4 x = *(const float4*)(p + j);
                v[j] = x.x; v[j + 1] = x.y; v[j + 2] = x.z; v[j + 3] = x.w;
            }
        } else {
#pragma unroll
            for (int j = 0; j < 16; ++j) v[j] = 0.f;
        }
#pragma unroll
        for (int j = 0; j < 16; ++j) At[kc + j][row] = v[j];
        const float* wp = W + row * 64 + kc;
#pragma unroll
        for (int j = 0; j < 16; j += 4)
            *(float4*)&Wl[row][kc + j] = *(const float4*)(wp + j);
    }
    __syncthreads();
    int m0 = (t & 15) * 4, n0 = (t >> 4) * 4;
    float acc[4][4];
#pragma unroll
    for (int i = 0; i < 4; ++i)
#pragma unroll
        for (int j = 0; j < 4; ++j) acc[i][j] = 0.f;
#pragma unroll 8
    for (int kk = 0; kk < 64; ++kk) {
        float4 a = *(const float4*)&At[kk][m0];
        float4 b = *(const float4*)&Wl[kk][n0];
        float av[4] = {a.x, a.y, a.z, a.w};
        float bv[4] = {b.x, b.y, b.z, b.w};
#pragma unroll
        for (int i = 0; i < 4; ++i)
#pragma unroll
            for (int j = 0; j < 4; ++j) acc[i][j] = fmaf(av[i], bv[j], acc[i][j]);
    }
#pragma unroll
    for (int i = 0; i < 4; ++i) {
        int r = bm + m0 + i;
        if (r < N) {
            float dv = dis[r];
            ushort4 o;
            o.x = f2bf(acc[i][0] * dv);
            o.y = f2bf(acc[i][1] * dv);
            o.z = f2bf(acc[i][2] * dv);
            o.w = f2bf(acc[i][3] * dv);
            *(ushort4*)&out[(size_t)r * 64 + n0] = o;
        }
    }
}

// ---------------- aggregation: one node per wave, bf16 gathers (128 B/edge) ----------------

__global__ __launch_bounds__(256) void k_agg(const unsigned short* __restrict__ xw,
                                             const int* __restrict__ offs,
                                             const int* __restrict__ src,
                                             const float* __restrict__ dis,
                                             const float* __restrict__ sc,
                                             const float* __restrict__ sh,
                                             const float* __restrict__ skip,
                                             float* __restrict__ out,
                                             int ld, int N) {
    int t = threadIdx.x;
    int lane = t & 63;
    int w = t >> 6;
    int v = blockIdx.x * 4 + w;
    if (v >= N) return;
    int es = lane >> 4;         // edge slot 0..3
    int f4 = lane & 15;         // 4-channel group
    int c0 = f4 * 4;
    const unsigned short* xp = xw + c0;
    float ax = 0.f, ay = 0.f, az = 0.f, aw_ = 0.f;
    int e0 = offs[v], e1 = offs[v + 1];
    int deg = e1 - e0;
    int k = 0;
    for (; k + 16 <= deg; k += 16) {
        int ld16 = (lane < 16) ? src[e0 + k + lane] : 0;
        int s0 = __shfl(ld16, es);
        int s1 = __shfl(ld16, es + 4);
        int s2 = __shfl(ld16, es + 8);
        int s3 = __shfl(ld16, es + 12);
        ushort4 m0 = *(const ushort4*)(xp + (size_t)s0 * 64);
        ushort4 m1 = *(const ushort4*)(xp + (size_t)s1 * 64);
        ushort4 m2 = *(const ushort4*)(xp + (size_t)s2 * 64);
        ushort4 m3 = *(const ushort4*)(xp + (size_t)s3 * 64);
        ax += (bf2f(m0.x) + bf2f(m1.x)) + (bf2f(m2.x) + bf2f(m3.x));
        ay += (bf2f(m0.y) + bf2f(m1.y)) + (bf2f(m2.y) + bf2f(m3.y));
        az += (bf2f(m0.z) + bf2f(m1.z)) + (bf2f(m2.z) + bf2f(m3.z));
        aw_ += (bf2f(m0.w) + bf2f(m1.w)) + (bf2f(m2.w) + bf2f(m3.w));
    }
    for (; k + 4 <= deg; k += 4) {
        int ld4 = (lane < 4) ? src[e0 + k + lane] : 0;
        int s0 = __shfl(ld4, es);
        ushort4 m0 = *(const ushort4*)(xp + (size_t)s0 * 64);
        ax += bf2f(m0.x); ay += bf2f(m0.y); az += bf2f(m0.z); aw_ += bf2f(m0.w);
    }
    int rem = deg - k;
    if (es < rem) {
        int s0 = src[e0 + k + es];
        ushort4 m0 = *(const ushort4*)(xp + (size_t)s0 * 64);
        ax += bf2f(m0.x); ay += bf2f(m0.y); az += bf2f(m0.z); aw_ += bf2f(m0.w);
    }
    ax += __shfl_xor(ax, 16); ay += __shfl_xor(ay, 16);
    az += __shfl_xor(az, 16); aw_ += __shfl_xor(aw_, 16);
    ax += __shfl_xor(ax, 32); ay += __shfl_xor(ay, 32);
    az += __shfl_xor(az, 32); aw_ += __shfl_xor(aw_, 32);
    if (es == 0) {
        ushort4 a = *(const ushort4*)(xp + (size_t)v * 64);   // self loop
        ax += bf2f(a.x); ay += bf2f(a.y); az += bf2f(a.z); aw_ += bf2f(a.w);
        float dv = dis[v];
        float4 S = *(const float4*)&sc[c0];
        float4 H = *(const float4*)&sh[c0];
        float y0 = fmaxf(fmaf(ax * dv, S.x, H.x), 0.f);
        float y1 = fmaxf(fmaf(ay * dv, S.y, H.y), 0.f);
        float y2 = fmaxf(fmaf(az * dv, S.z, H.z), 0.f);
        float y3 = fmaxf(fmaf(aw_ * dv, S.w, H.w), 0.f);
        size_t ob = (size_t)v * ld + c0;
        if (skip) {
            const float4 s4 = *(const float4*)(skip + ob);
            y0 += s4.x; y1 += s4.y; y2 += s4.z; y3 += s4.w;
        }
        float4 o; o.x = y0; o.y = y1; o.z = y2; o.w = y3;
        *(float4*)(out + ob) = o;
    }
}

// ---------------- encoder GEMM via bf16x3-split MFMA, LDS-staged A ----------------

__global__ __launch_bounds__(256) void k_encm(const float* __restrict__ A, int lda,
                                              int M, int K,
                                              const unsigned short* __restrict__ BhiT,
                                              const unsigned short* __restrict__ BloT,
                                              const float* __restrict__ bias,
                                              float* __restrict__ C, int ldc, int NWN) {
    extern __shared__ char smem[];
    const int BM = 128 / NWN;
    const int PS = BM * 5 + 1;
    short8* Ah = (short8*)smem;
    short8* Al = Ah + 4 * PS;

    int t = threadIdx.x;
    int lane = t & 63;
    int l16 = lane & 15;
    int quad = lane >> 4;
    int w = t >> 6;
    int nw = w % NWN;
    int mw = (w / NWN) * 32;
    int bm = blockIdx.x * BM;
    int n0 = nw * 64;

    floatx4 acc[2][4];
#pragma unroll
    for (int i = 0; i < 2; ++i)
#pragma unroll
        for (int j = 0; j < 4; ++j) acc[i][j] = (floatx4)0.f;

    const unsigned short* bp[4];
#pragma unroll
    for (int j = 0; j < 4; ++j)
        bp[j] = BhiT + (size_t)(n0 + j * 16 + l16) * K + quad * 8;
    size_t loOff = (size_t)(BloT - BhiT);

    const int ngroups = BM / 32;
    int grow = t >> 3;
    int c0 = (t & 7) * 16;

    for (int k0 = 0; k0 < K; k0 += 128) {
        if (k0) __syncthreads();
        for (int g = 0; g < ngroups; ++g) {
            int row = g * 32 + grow;
            int r = bm + row;
            float v[16];
            if (r < M) {
                const float* p = A + (size_t)r * lda + k0 + c0;
#pragma unroll
                for (int j = 0; j < 16; j += 4) {
                    float4 x = *(const float4*)(p + j);
                    v[j] = x.x; v[j + 1] = x.y; v[j + 2] = x.z; v[j + 3] = x.w;
                }
            } else {
#pragma unroll
                for (int j = 0; j < 16; ++j) v[j] = 0.f;
            }
#pragma unroll
            for (int q = 0; q < 2; ++q) {
                short8 hi, lo;
#pragma unroll
                for (int jj = 0; jj < 8; ++jj) {
                    float a = v[q * 8 + jj];
                    unsigned b = __float_as_uint(a);
                    unsigned hb = b & 0xFFFF0000u;
                    hi[jj] = (short)(hb >> 16);
                    float al = a - __uint_as_float(hb);
                    lo[jj] = (short)(__float_as_uint(al) >> 16);
                }
                int cc = c0 + q * 8;
                int u = (cc >> 5) * PS + row * 5 + ((cc & 31) >> 3);
                Ah[u] = hi;
                Al[u] = lo;
            }
        }
        __syncthreads();
#pragma unroll
        for (int kc = 0; kc < 4; ++kc) {
            int ub0 = kc * PS + (mw + l16) * 5 + quad;
            int ub1 = kc * PS + (mw + 16 + l16) * 5 + quad;
            short8 ah0 = Ah[ub0];
            short8 ah1 = Ah[ub1];
            short8 al0 = Al[ub0];
            short8 al1 = Al[ub1];
            int koff = k0 + kc * 32;
            short8 bh[4], bl[4];
#pragma unroll
            for (int j = 0; j < 4; ++j) {
                bh[j] = *(const short8*)(bp[j] + koff);
                bl[j] = *(const short8*)(bp[j] + loOff + koff);
            }
#pragma unroll
            for (int j = 0; j < 4; ++j) {
                acc[0][j] = __builtin_amdgcn_mfma_f32_16x16x32_bf16(al0, bh[j], acc[0][j], 0, 0, 0);
                acc[0][j] = __builtin_amdgcn_mfma_f32_16x16x32_bf16(ah0, bl[j], acc[0][j], 0, 0, 0);
                acc[0][j] = __builtin_amdgcn_mfma_f32_16x16x32_bf16(ah0, bh[j], acc[0][j], 0, 0, 0);
                acc[1][j] = __builtin_amdgcn_mfma_f32_16x16x32_bf16(al1, bh[j], acc[1][j], 0, 0, 0);
                acc[1][j] = __builtin_amdgcn_mfma_f32_16x16x32_bf16(ah1, bl[j], acc[1][j], 0, 0, 0);
                acc[1][j] = __builtin_amdgcn_mfma_f32_16x16x32_bf16(ah1, bh[j], acc[1][j], 0, 0, 0);
            }
        }
    }

#pragma unroll
    for (int i = 0; i < 2; ++i) {
#pragma unroll
        for (int r = 0; r < 4; ++r) {
            int m = bm + mw + i * 16 + quad * 4 + r;
            if (m < M) {
                float* cp = C + (size_t)m * ldc + n0 + l16;
#pragma unroll
                for (int j = 0; j < 4; ++j)
                    cp[j * 16] = fmaxf(acc[i][j][r] + bias[n0 + j * 16 + l16], 0.f);
            }
        }
    }
}

// ---------------- graph mean-pool ----------------

__global__ __launch_bounds__(256) void k_pool(const float* __restrict__ h2,
                                              const int* __restrict__ gstart,
                                              float* __restrict__ gsum, int H) {
    int g = blockIdx.x / SMAX;
    int s = blockIdx.x % SMAX;
    int base = gstart[g], end = gstart[g + 1];
    int cnt = end - base;
    if (cnt <= 0) return;
    int per = (cnt + SMAX - 1) / SMAX;
    int n0 = base + s * per;
    int n1 = n0 + per; if (n1 > end) n1 = end;
    if (n0 >= n1) return;
    int t = threadIdx.x;
    int q = t & 31;
    int c = q * 4;
    int sub = t >> 5;
    float4 acc = make_float4(0.f, 0.f, 0.f, 0.f);
    for (int n = n0 + sub; n < n1; n += 8) {
        float4 v = *(const float4*)(h2 + (size_t)n * H + c);
        acc.x += v.x; acc.y += v.y; acc.z += v.z; acc.w += v.w;
    }
    __shared__ float4 red[8][32];
    red[sub][q] = acc;
    __syncthreads();
    if (sub == 0) {
        float4 a = red[0][q];
#pragma unroll
        for (int i = 1; i < 8; ++i) {
            float4 b = red[i][q];
            a.x += b.x; a.y += b.y; a.z += b.z; a.w += b.w;
        }
        atomicAdd(&gsum[(size_t)g * H + c + 0], a.x);
        atomicAdd(&gsum[(size_t)g * H + c + 1], a.y);
        atomicAdd(&gsum[(size_t)g * H + c + 2], a.z);
        atomicAdd(&gsum[(size_t)g * H + c + 3], a.w);
    }
}

// ---------------- decoder ----------------

__global__ void k_dec(const float* __restrict__ gsum, const int* __restrict__ gstart,
                      const float* __restrict__ W1, const float* __restrict__ b1,
                      const float* __restrict__ W2, const float* __restrict__ b2,
                      float* __restrict__ out, int H, int HD) {
    int g = blockIdx.x;
    int t = threadIdx.x;
    float cnt = (float)(gstart[g + 1] - gstart[g]);
    float inv = 1.0f / fmaxf(cnt, 1.0f);
    float hid = b1[t];
    for (int k = 0; k < H; ++k) {
        float gf = gsum[(size_t)g * H + k] * inv;
        hid = fmaf(gf, W1[k * HD + t], hid);
    }
    hid = fmaxf(hid, 0.f);
    float p = hid * W2[t];
    for (int off = 32; off > 0; off >>= 1) p += __shfl_down(p, off);
    if (t == 0) out[g] = p + b2[0];
}

// ---------------- host ----------------

extern "C" void kernel_launch(void* const* d_in, const int* in_sizes, int n_in,
                              void* d_out, int out_size, void* d_ws, size_t ws_size,
                              hipStream_t stream) {
    const float* x     = (const float*)d_in[0];
    const int*   ei    = (const int*)d_in[1];
    const int*   batch = (const int*)d_in[2];
    const float* convW = (const float*)d_in[3];
    const float* convb = (const float*)d_in[4];
    const float* gamma = (const float*)d_in[5];
    const float* beta  = (const float*)d_in[6];
    const float* mean  = (const float*)d_in[7];
    const float* var   = (const float*)d_in[8];
    const float* eW1   = (const float*)d_in[9];
    const float* eb1   = (const float*)d_in[10];
    const float* eW2   = (const float*)d_in[11];
    const float* eb2   = (const float*)d_in[12];
    const float* dW1   = (const float*)d_in[13];
    const float* db1   = (const float*)d_in[14];
    const float* dW2   = (const float*)d_in[15];
    const float* db2   = (const float*)d_in[16];

    int N  = in_sizes[0] / D;
    int E  = in_sizes[1] / 2;
    int L  = in_sizes[3] / (D * D);
    int G  = out_size;
    int LD = L * D;                 // 256
    int H1 = in_sizes[10];          // 256
    int H2 = in_sizes[12];          // 128
    int HD = in_sizes[14];          // 64
    int NBK = (N + 255) >> 8;       // 391

    char* ws = (char*)d_ws;
    size_t off = 0;
    auto alloc = [&](size_t b) -> void* {
        void* p = ws + off;
        off += (b + 255) & ~(size_t)255;
        return p;
    };
    float* local  = (float*)alloc((size_t)N * LD * 4);   // layer outputs; later h2
    float* bufB   = (float*)alloc((size_t)N * LD * 4);   // part pairs / xw(bf16) / h1
    int*   csrc   = (int*)alloc((size_t)E * 4);
    float* dis    = (float*)alloc((size_t)N * 4);
    int*   offs   = (int*)alloc((size_t)(N + 1) * 4);
    int*   ghist  = (int*)alloc((size_t)NBK * 4);
    int*   bstart = (int*)alloc((size_t)(NBK + 1) * 4);
    int*   gcur   = (int*)alloc((size_t)NBK * 4);
    float* sc     = (float*)alloc((size_t)LD * 4);
    float* sh     = (float*)alloc((size_t)LD * 4);
    float* gsum   = (float*)alloc((size_t)G * H2 * 4);
    int*   gstart = (int*)alloc((size_t)(G + 1) * 4);
    unsigned short* w1hi = (unsigned short*)alloc((size_t)LD * H1 * 2);
    unsigned short* w1lo = (unsigned short*)alloc((size_t)LD * H1 * 2);
    unsigned short* w2hi = (unsigned short*)alloc((size_t)H1 * H2 * 2);
    unsigned short* w2lo = (unsigned short*)alloc((size_t)H1 * H2 * 2);
    int2* part = (int2*)bufB;              // aliases bufB; dead before first k_conv
    unsigned short* xw = (unsigned short*)bufB;  // bf16 [N][64] message table
    float* h1 = bufB;
    float* h2 = local;

    hipMemsetAsync(ghist, 0, (size_t)NBK * 4, stream);
    hipMemsetAsync(gsum, 0, (size_t)G * H2 * 4, stream);

    int nchunks = (E + 8191) / 8192;
    k_hist<<<nchunks, 256, NBK * 4, stream>>>(ei + E, ghist, E, NBK);
    k_bscan<<<1, 512, 0, stream>>>(ghist, bstart, gcur, offs, NBK, N, E);
    k_part<<<nchunks, 256, 2 * NBK * 4, stream>>>(ei, ei + E, gcur, part, E, NBK);
    k_bucket<<<NBK, 256, 0, stream>>>(part, bstart, offs, dis, csrc, N);
    k_gb<<<1, 128, 0, stream>>>(batch, gstart, N, G);
    k_bnprep<<<(LD + 255) / 256, 256, 0, stream>>>(convb, gamma, beta, mean, var, sc, sh, LD);
    k_wsplit<<<(LD * H1 + 255) / 256, 256, 0, stream>>>(eW1, w1hi, w1lo, LD, H1, 8);
    k_wsplit<<<(H1 * H2 + 255) / 256, 256, 0, stream>>>(eW2, w2hi, w2lo, H1, H2, 7);

    for (int l = 0; l < L; ++l) {
        const float* Ain = (l == 0) ? x : (local + (size_t)(l - 1) * D);
        int lda = (l == 0) ? D : LD;
        k_conv<<<(N + 63) / 64, 256, 0, stream>>>(Ain, lda, convW + (size_t)l * D * D, dis, xw, N);
        const float* skip = (l % 2 == 0 && l != 0 && l != L - 1) ? (local + (size_t)(l - 2) * D) : nullptr;
        k_agg<<<(N + 3) / 4, 256, 0, stream>>>(xw, offs, csrc, dis, sc + (size_t)l * D,
                                               sh + (size_t)l * D, skip,
                                               local + (size_t)l * D, LD, N);
    }

    {
        int BM = 32, PS = BM * 5 + 1;
        size_t shb = (size_t)2 * 4 * PS * 16;
        k_encm<<<(N + BM - 1) / BM, 256, shb, stream>>>(local, LD, N, LD, w1hi, w1lo, eb1, h1, H1, 4);
    }
    {
        int BM = 64, PS = BM * 5 + 1;
        size_t shb = (size_t)2 * 4 * PS * 16;
        k_encm<<<(N + BM - 1) / BM, 256, shb, stream>>>(h1, H1, N, H1, w2hi, w2lo, eb2, h2, H2, 2);
    }

    k_pool<<<G * SMAX, 256, 0, stream>>>(h2, gstart, gsum, H2);
    k_dec<<<G, HD, 0, stream>>>(gsum, gstart, dW1, db1, dW2, db2, (float*)d_out, H2, HD);
}